// Round 9
// baseline (339.420 us; speedup 1.0000x reference)
//
#include <hip/hip_runtime.h>
#include <hip/hip_fp16.h>
#include <math.h>

#define BB   4
#define C_   128
#define H_   96
#define W_   192
#define COUT 128
#define DG_  2
#define CG_  64
#define K_   9
#define HO   96
#define WO   192
#define HW   (H_ * W_)       // 18432
#define OMCH 54
#define RDIM (C_ * K_)       // 1152
#define NKS  (RDIM / 32)     // 36 K-steps

typedef __attribute__((ext_vector_type(8))) short bf16x8;
typedef __attribute__((ext_vector_type(4))) float f32x4;

static __device__ __forceinline__ ushort f2bf(float f) {
  union { float f; uint u; } v; v.f = f;
  uint r = v.u + 0x7fff + ((v.u >> 16) & 1);   // RNE
  return (ushort)(r >> 16);
}

// ---------------------------------------------------------------------------
// Prep: bf16 weights, k-major orderings (proven).
// ---------------------------------------------------------------------------
__global__ __launch_bounds__(256) void prep_k(
    const float* __restrict__ wd, const float* __restrict__ wo,
    ushort* __restrict__ Wt, ushort* __restrict__ Awo) {
  int i = blockIdx.x * 256 + threadIdx.x;
  if (i < 128 * RDIM) {
    int o = i / RDIM, r = i - o * RDIM;
    int g = r / 576, t = r - g * 576;
    int k = t >> 6, cg = t & 63;
    Wt[i] = f2bf(wd[((size_t)o * C_ + g * 64 + cg) * 9 + k]);
  }
  if (i < 64 * RDIM) {
    int o2 = i / RDIM, r = i - o2 * RDIM;
    int k = r >> 7, c = r & 127;
    int g = o2 >> 5, j = o2 & 31;
    float v = (((c >> 6) == g) && (j < 27))
                ? wo[(((size_t)(g * 27 + j)) * 64 + (c & 63)) * 9 + k] : 0.f;
    Awo[i] = f2bf(v);
  }
}

// ---------------------------------------------------------------------------
// NCHW -> NHWC transpose of x: xT[b][p][c] = x[b][c][p]. 1152 blocks.
// ---------------------------------------------------------------------------
__global__ __launch_bounds__(256) void xt_k(
    const float* __restrict__ x, float* __restrict__ xT) {
  __shared__ float t[128][65];
  int blk = blockIdx.x;
  int b = blk / 288, p0 = (blk % 288) * 64;
  int q = threadIdx.x >> 6, l = threadIdx.x & 63;
  const float* xb = x + (size_t)b * C_ * HW;
#pragma unroll
  for (int it = 0; it < 32; ++it) {
    int c = q * 32 + it;
    t[c][l] = xb[(size_t)c * HW + p0 + l];
  }
  __syncthreads();
  float* xTb = xT + (size_t)b * HW * 128;
#pragma unroll
  for (int it = 0; it < 32; ++it) {
    int px = q * 16 + (it >> 1);
    int c = (it & 1) * 64 + l;
    xTb[(size_t)(p0 + px) * 128 + c] = t[c][px];
  }
}

// ---------------------------------------------------------------------------
// Offset conv as MFMA (R3 exact — proven deterministic).
// ---------------------------------------------------------------------------
__global__ __launch_bounds__(256) void offset_mfma_k(
    const float* __restrict__ x, const ushort* __restrict__ Awo,
    const float* __restrict__ b_offset, float* __restrict__ om) {
  __shared__ uint s_val[2][64][20];

  int bid = blockIdx.x;
  int blk = (bid & 7) * 144 + (bid >> 3);
  int wt = blk % 3, bh = blk / 3;
  int ho = bh % HO, b = bh / HO;
  int wo0 = wt * 64;
  int lane = threadIdx.x & 63, wv = threadIdx.x >> 6;

  const float* xb = x + (size_t)b * C_ * HW;
  f32x4 acc[4];
#pragma unroll
  for (int n = 0; n < 4; ++n) acc[n] = (f32x4){0.f, 0.f, 0.f, 0.f};

  const ushort* abase = Awo + (size_t)(wv * 16 + (lane & 15)) * RDIM + (lane >> 4) * 8;

  float gv[8];

  auto patch_gather = [&](int step) {
    int k = step >> 2;
    int dy = k / 3, dx = k - dy * 3;
    int y  = ho - 2 + 2 * dy;
    int xc = wo0 + lane - 2 + 2 * dx;
    bool ok = (y >= 0) & (y < H_) & (xc >= 0) & (xc < W_);
    int c0 = (step & 3) * 32 + wv * 8;
    const float* pl = xb + ((ptrdiff_t)c0 * HW + y * W_ + xc);
#pragma unroll
    for (int j = 0; j < 8; ++j) { gv[j] = ok ? *pl : 0.f; pl += HW; }
  };

  auto patch_finish = [&](int nb) {
    uint res[4];
#pragma unroll
    for (int j = 0; j < 8; ++j) {
      uint bf = (uint)f2bf(gv[j]);
      if (j & 1) res[j >> 1] |= bf << 16; else res[j >> 1] = bf;
    }
    *(int4*)&s_val[nb][lane][wv * 4] = *(int4*)&res[0];
  };

  auto mfma_step = [&](int step, int cb) {
    bf16x8 af = *(const bf16x8*)(abase + step * 32);
#pragma unroll
    for (int n = 0; n < 4; ++n) {
      bf16x8 bfr = *(const bf16x8*)&s_val[cb][n * 16 + (lane & 15)][(lane >> 4) * 4];
      acc[n] = __builtin_amdgcn_mfma_f32_16x16x32_bf16(af, bfr, acc[n], 0, 0, 0);
    }
  };

  patch_gather(0);
  patch_finish(0);
  __syncthreads();
  for (int it = 0; it < NKS - 1; ++it) {
    patch_gather(it + 1);
    mfma_step(it, it & 1);
    patch_finish((it + 1) & 1);
    __syncthreads();
  }
  mfma_step(NKS - 1, (NKS - 1) & 1);

  int col = lane & 15, rgrp = lane >> 4;
#pragma unroll
  for (int n = 0; n < 4; ++n)
#pragma unroll
    for (int ri = 0; ri < 4; ++ri) {
      int o2 = wv * 16 + rgrp * 4 + ri;
      int g = o2 >> 5, j = o2 & 31;
      if (j < 27) {
        int ch = g * 27 + j;
        om[((size_t)(b * OMCH + ch) * HO + ho) * WO + wo0 + n * 16 + col] =
            acc[n][ri] + b_offset[ch];
      }
    }
}

// ---------------------------------------------------------------------------
// Tile-fused main kernel, NHWC gathers. Block = 16 px x 128 Cout, 4608 blocks.
// Phase 1 (barrier-free): thread=(px,slot), 9 tasks; task = (gk, ch-oct):
//   1 coef -> 8 coalesced float4 (4 corners x 8ch contiguous) -> int4 LDS write.
// Phase 2: GEMM from LDS (R8-proven: 72 MFMA/wave, A depth-2 prefetch).
// ---------------------------------------------------------------------------
#define GE(G, bq, j) (G[(bq) + ((j) >> 2)][(j) & 3])

__global__ __launch_bounds__(256) void deform_tile_k(
    const float* __restrict__ xT, const float* __restrict__ om,
    const ushort* __restrict__ Wt, float* __restrict__ out) {
  __shared__ uint  s_addr[288];            // 1152 B: [gk][px] NHWC base (pre-*128)
  __shared__ uint2 s_wq[288];              // 2304 B
  __shared__ uint  s_val[NKS * 16 * 16];   // 36864 B: [step][px][rk/2]

  int bid = blockIdx.x;
  int blk = (bid & 7) * 576 + (bid >> 3);  // bijective, 4608 % 8 == 0
  int pt = blk % 1152, b = blk / 1152;
  int ho = pt / 12, wo0 = (pt % 12) * 16;
  int tid = threadIdx.x;

  // ---- phase 0: canonical in-bounds bilinear coefficients (proven math) ----
  for (int e = tid; e < 288; e += 256) {
    int px = e & 15, gk = e >> 4;
    int g = gk / 9, k = gk - g * 9;
    int wo = wo0 + px;
    const float* omb = om + (size_t)b * OMCH * HW + (size_t)ho * WO + wo;
    float offy = omb[(size_t)(g * 18 + k * 2 + 0) * HW];
    float offx = omb[(size_t)(g * 18 + k * 2 + 1) * HW];
    float z    = omb[(size_t)(36 + g * 9 + k) * HW];
    float msk  = 2.f / (1.f + __expf(-z));
    float py = (float)(ho - 2 + (k / 3) * 2) + offy;
    float px_ = (float)(wo - 2 + (k % 3) * 2) + offx;
    float y0f = floorf(py), x0f = floorf(px_);
    int   y0 = (int)y0f, x0 = (int)x0f;
    float ty = py - y0f, tx = px_ - x0f;
    float wy0 = (y0 >= 0 && y0 < H_)      ? (1.f - ty) : 0.f;
    float wy1 = (y0 >= -1 && y0 < H_ - 1) ? ty         : 0.f;
    float wx0 = (x0 >= 0 && x0 < W_)      ? (1.f - tx) : 0.f;
    float wx1 = (x0 >= -1 && x0 < W_ - 1) ? tx         : 0.f;
    int yb  = min(max(y0, 0), H_ - 2);
    int xb_ = min(max(x0, 0), W_ - 2);
    float wAy = (y0 == yb      ? wy0 : 0.f) + (y0 + 1 == yb      ? wy1 : 0.f);
    float wBy = (y0 == yb + 1  ? wy0 : 0.f) + (y0 + 1 == yb + 1  ? wy1 : 0.f);
    float wAx = (x0 == xb_     ? wx0 : 0.f) + (x0 + 1 == xb_     ? wx1 : 0.f);
    float wBx = (x0 == xb_ + 1 ? wx0 : 0.f) + (x0 + 1 == xb_ + 1 ? wx1 : 0.f);
    s_addr[e] = (uint)((yb * W_ + xb_) * 128);
    union { __half2 h; uint u; } uA, uB;
    uA.h = __half2{__float2half(wAy * wAx * msk), __float2half(wAy * wBx * msk)};
    uB.h = __half2{__float2half(wBy * wAx * msk), __float2half(wBy * wBx * msk)};
    s_wq[e] = make_uint2(uA.u, uB.u);
  }
  __syncthreads();

  // ---- phase 1: sample all 1152 r x 16 px into LDS, no barriers ----
  {
    int px = tid & 15, slot = tid >> 4;
    const float* xTb = xT + (size_t)b * HW * 128;

    f32x4 A[8], B[8];
    float2 wAa, wBa, wAb, wBb;
    int stA, ofA, stB, ofB;

    auto load_task = [&](int i, f32x4 (&G)[8], float2& wAo, float2& wBo,
                         int& stepo, int& uofso) {
      int t = slot + 16 * i;
      int gk = t >> 3, oct = t & 7;
      int g = (gk >= 9), k = gk - g * 9;
      int ci = gk * 16 + px;
      uint base = s_addr[ci];
      uint2 wq = s_wq[ci];
      union { __half2 h; uint u; } uA, uB;
      uA.u = wq.x; uB.u = wq.y;
      float2 a = __half22float2(uA.h);
      float2 bq = __half22float2(uB.h);
      wAo = a; wBo = bq;
      const float* p00 = xTb + base + g * 64 + oct * 8;
      G[0] = *(const f32x4*)(p00);
      G[1] = *(const f32x4*)(p00 + 4);
      G[2] = *(const f32x4*)(p00 + 128);          // x+1
      G[3] = *(const f32x4*)(p00 + 132);
      G[4] = *(const f32x4*)(p00 + W_ * 128);     // y+1
      G[5] = *(const f32x4*)(p00 + W_ * 128 + 4);
      G[6] = *(const f32x4*)(p00 + W_ * 128 + 128);
      G[7] = *(const f32x4*)(p00 + W_ * 128 + 132);
      stepo = g * 18 + k * 2 + (oct >> 2);
      uofso = (oct & 3) * 4;
    };

    auto finish_task = [&](const f32x4 (&G)[8], float2 wA, float2 wB,
                           int step, int uofs) {
      uint res[4];
#pragma unroll
      for (int jj = 0; jj < 4; ++jj) {
        int j0 = 2 * jj, j1 = 2 * jj + 1;
        float v0 = wA.x * GE(G, 0, j0) + wA.y * GE(G, 2, j0)
                 + wB.x * GE(G, 4, j0) + wB.y * GE(G, 6, j0);
        float v1 = wA.x * GE(G, 0, j1) + wA.y * GE(G, 2, j1)
                 + wB.x * GE(G, 4, j1) + wB.y * GE(G, 6, j1);
        res[jj] = (uint)f2bf(v0) | ((uint)f2bf(v1) << 16);
      }
      int base = (step * 16 + px) * 16 + uofs;
      *(int4*)&s_val[base] = *(int4*)&res[0];
    };

    load_task(0, A, wAa, wBa, stA, ofA);
#pragma unroll
    for (int i2 = 0; i2 < 9; i2 += 2) {
      if (i2 + 1 < 9) load_task(i2 + 1, B, wAb, wBb, stB, ofB);
      finish_task(A, wAa, wBa, stA, ofA);
      if (i2 + 1 < 9) {
        if (i2 + 2 < 9) load_task(i2 + 2, A, wAa, wBa, stA, ofA);
        finish_task(B, wAb, wBb, stB, ofB);
      }
    }
  }
  __syncthreads();

  // ---- phase 2: GEMM from LDS (R8-proven) ----
  int lane = tid & 63, wv = tid >> 6;
  int col = lane & 15, oct = lane >> 4;

  const ushort* wb0 = Wt + (size_t)(wv * 32 + col) * RDIM + oct * 8;
  const ushort* wb1 = wb0 + (size_t)16 * RDIM;

  f32x4 acc[2];
  acc[0] = (f32x4){0.f, 0.f, 0.f, 0.f};
  acc[1] = (f32x4){0.f, 0.f, 0.f, 0.f};

  bf16x8 a0_0 = *(const bf16x8*)(wb0);
  bf16x8 a1_0 = *(const bf16x8*)(wb1);
  bf16x8 a0_1 = *(const bf16x8*)(wb0 + 32);
  bf16x8 a1_1 = *(const bf16x8*)(wb1 + 32);

  for (int it2 = 0; it2 < NKS; it2 += 2) {
    {
      bf16x8 pa0 = a0_0, pa1 = a1_0;
      if (it2 + 2 < NKS) {
        a0_0 = *(const bf16x8*)(wb0 + (it2 + 2) * 32);
        a1_0 = *(const bf16x8*)(wb1 + (it2 + 2) * 32);
      }
      bf16x8 bfr = *(const bf16x8*)&s_val[(it2 * 16 + col) * 16 + oct * 4];
      acc[0] = __builtin_amdgcn_mfma_f32_16x16x32_bf16(pa0, bfr, acc[0], 0, 0, 0);
      acc[1] = __builtin_amdgcn_mfma_f32_16x16x32_bf16(pa1, bfr, acc[1], 0, 0, 0);
    }
    {
      bf16x8 pa0 = a0_1, pa1 = a1_1;
      if (it2 + 3 < NKS) {
        a0_1 = *(const bf16x8*)(wb0 + (it2 + 3) * 32);
        a1_1 = *(const bf16x8*)(wb1 + (it2 + 3) * 32);
      }
      bf16x8 bfr = *(const bf16x8*)&s_val[((it2 + 1) * 16 + col) * 16 + oct * 4];
      acc[0] = __builtin_amdgcn_mfma_f32_16x16x32_bf16(pa0, bfr, acc[0], 0, 0, 0);
      acc[1] = __builtin_amdgcn_mfma_f32_16x16x32_bf16(pa1, bfr, acc[1], 0, 0, 0);
    }
  }

#pragma unroll
  for (int m = 0; m < 2; ++m)
#pragma unroll
    for (int ri = 0; ri < 4; ++ri) {
      int o = wv * 32 + m * 16 + oct * 4 + ri;
      out[((size_t)(b * COUT + o) * HO + ho) * WO + wo0 + col] = acc[m][ri];
    }
}

// ---------------------------------------------------------------------------
extern "C" void kernel_launch(void* const* d_in, const int* in_sizes, int n_in,
                              void* d_out, int out_size, void* d_ws, size_t ws_size,
                              hipStream_t stream) {
  const float* x        = (const float*)d_in[0];
  const float* w_offset = (const float*)d_in[1];
  const float* b_offset = (const float*)d_in[2];
  const float* w_deform = (const float*)d_in[3];
  float* out = (float*)d_out;

  char* ws = (char*)d_ws;
  float*  om  = (float*)ws;                             // 15,925,248 B
  ushort* Wt  = (ushort*)(ws + 15925248);               //    294,912 B
  ushort* Awo = (ushort*)(ws + 15925248 + 294912);      //    147,456 B
  float*  xT  = (float*)(ws + 15925248 + 294912 + 147456);  // 37,748,736 B (ws >= 101MB per R7)

  prep_k<<<576, 256, 0, stream>>>(w_deform, w_offset, Wt, Awo);
  xt_k<<<1152, 256, 0, stream>>>(x, xT);
  offset_mfma_k<<<1152, 256, 0, stream>>>(x, Awo, b_offset, om);
  deform_tile_k<<<4608, 256, 0, stream>>>(xT, om, Wt, out);
}

// Round 10
// 283.812 us; speedup vs baseline: 1.1959x; 1.1959x over previous
//
#include <hip/hip_runtime.h>
#include <hip/hip_fp16.h>
#include <math.h>

#define BB   4
#define C_   128
#define H_   96
#define W_   192
#define COUT 128
#define DG_  2
#define CG_  64
#define K_   9
#define HO   96
#define WO   192
#define HW   (H_ * W_)       // 18432
#define OMCH 54
#define RDIM (C_ * K_)       // 1152
#define NKS  (RDIM / 32)     // 36 K-steps

typedef __attribute__((ext_vector_type(8))) short bf16x8;
typedef __attribute__((ext_vector_type(4))) float f32x4;

static __device__ __forceinline__ ushort f2bf(float f) {
  union { float f; uint u; } v; v.f = f;
  uint r = v.u + 0x7fff + ((v.u >> 16) & 1);   // RNE
  return (ushort)(r >> 16);
}

// ---------------------------------------------------------------------------
// Prep: bf16 weights, k-major orderings (proven).
// ---------------------------------------------------------------------------
__global__ __launch_bounds__(256) void prep_k(
    const float* __restrict__ wd, const float* __restrict__ wo,
    ushort* __restrict__ Wt, ushort* __restrict__ Awo) {
  int i = blockIdx.x * 256 + threadIdx.x;
  if (i < 128 * RDIM) {
    int o = i / RDIM, r = i - o * RDIM;
    int g = r / 576, t = r - g * 576;
    int k = t >> 6, cg = t & 63;
    Wt[i] = f2bf(wd[((size_t)o * C_ + g * 64 + cg) * 9 + k]);
  }
  if (i < 64 * RDIM) {
    int o2 = i / RDIM, r = i - o2 * RDIM;
    int k = r >> 7, c = r & 127;
    int g = o2 >> 5, j = o2 & 31;
    float v = (((c >> 6) == g) && (j < 27))
                ? wo[(((size_t)(g * 27 + j)) * 64 + (c & 63)) * 9 + k] : 0.f;
    Awo[i] = f2bf(v);
  }
}

// ---------------------------------------------------------------------------
// NCHW -> NHWC transpose of x (proven in R9).
// ---------------------------------------------------------------------------
__global__ __launch_bounds__(256) void xt_k(
    const float* __restrict__ x, float* __restrict__ xT) {
  __shared__ float t[128][65];
  int blk = blockIdx.x;
  int b = blk / 288, p0 = (blk % 288) * 64;
  int q = threadIdx.x >> 6, l = threadIdx.x & 63;
  const float* xb = x + (size_t)b * C_ * HW;
#pragma unroll
  for (int it = 0; it < 32; ++it) {
    int c = q * 32 + it;
    t[c][l] = xb[(size_t)c * HW + p0 + l];
  }
  __syncthreads();
  float* xTb = xT + (size_t)b * HW * 128;
#pragma unroll
  for (int it = 0; it < 32; ++it) {
    int px = q * 16 + (it >> 1);
    int c = (it & 1) * 64 + l;
    xTb[(size_t)(p0 + px) * 128 + c] = t[c][px];
  }
}

// ---------------------------------------------------------------------------
// Offset conv as MFMA (R3 exact — proven deterministic).
// ---------------------------------------------------------------------------
__global__ __launch_bounds__(256) void offset_mfma_k(
    const float* __restrict__ x, const ushort* __restrict__ Awo,
    const float* __restrict__ b_offset, float* __restrict__ om) {
  __shared__ uint s_val[2][64][20];

  int bid = blockIdx.x;
  int blk = (bid & 7) * 144 + (bid >> 3);
  int wt = blk % 3, bh = blk / 3;
  int ho = bh % HO, b = bh / HO;
  int wo0 = wt * 64;
  int lane = threadIdx.x & 63, wv = threadIdx.x >> 6;

  const float* xb = x + (size_t)b * C_ * HW;
  f32x4 acc[4];
#pragma unroll
  for (int n = 0; n < 4; ++n) acc[n] = (f32x4){0.f, 0.f, 0.f, 0.f};

  const ushort* abase = Awo + (size_t)(wv * 16 + (lane & 15)) * RDIM + (lane >> 4) * 8;

  float gv[8];

  auto patch_gather = [&](int step) {
    int k = step >> 2;
    int dy = k / 3, dx = k - dy * 3;
    int y  = ho - 2 + 2 * dy;
    int xc = wo0 + lane - 2 + 2 * dx;
    bool ok = (y >= 0) & (y < H_) & (xc >= 0) & (xc < W_);
    int c0 = (step & 3) * 32 + wv * 8;
    const float* pl = xb + ((ptrdiff_t)c0 * HW + y * W_ + xc);
#pragma unroll
    for (int j = 0; j < 8; ++j) { gv[j] = ok ? *pl : 0.f; pl += HW; }
  };

  auto patch_finish = [&](int nb) {
    uint res[4];
#pragma unroll
    for (int j = 0; j < 8; ++j) {
      uint bf = (uint)f2bf(gv[j]);
      if (j & 1) res[j >> 1] |= bf << 16; else res[j >> 1] = bf;
    }
    *(int4*)&s_val[nb][lane][wv * 4] = *(int4*)&res[0];
  };

  auto mfma_step = [&](int step, int cb) {
    bf16x8 af = *(const bf16x8*)(abase + step * 32);
#pragma unroll
    for (int n = 0; n < 4; ++n) {
      bf16x8 bfr = *(const bf16x8*)&s_val[cb][n * 16 + (lane & 15)][(lane >> 4) * 4];
      acc[n] = __builtin_amdgcn_mfma_f32_16x16x32_bf16(af, bfr, acc[n], 0, 0, 0);
    }
  };

  patch_gather(0);
  patch_finish(0);
  __syncthreads();
  for (int it = 0; it < NKS - 1; ++it) {
    patch_gather(it + 1);
    mfma_step(it, it & 1);
    patch_finish((it + 1) & 1);
    __syncthreads();
  }
  mfma_step(NKS - 1, (NKS - 1) & 1);

  int col = lane & 15, rgrp = lane >> 4;
#pragma unroll
  for (int n = 0; n < 4; ++n)
#pragma unroll
    for (int ri = 0; ri < 4; ++ri) {
      int o2 = wv * 16 + rgrp * 4 + ri;
      int g = o2 >> 5, j = o2 & 31;
      if (j < 27) {
        int ch = g * 27 + j;
        om[((size_t)(b * OMCH + ch) * HO + ho) * WO + wo0 + n * 16 + col] =
            acc[n][ri] + b_offset[ch];
      }
    }
}

// ---------------------------------------------------------------------------
// Tile-fused main kernel, channel-lane NHWC gathers.
// Block = 16 px x 128 Cout, 4608 blocks.
// Phase 1: pair-task = (gk, px-pair); lane = (px-half, channel-pair cl).
//   4 x float2 corner loads per lane; each wave-load = two contiguous 256B
//   regions (8 lines total) — fully coalesced. Weight/base broadcast from LDS.
//   s_val written b32, XOR-chunk swizzled for conflict-free phase-2 reads.
// Phase 2: GEMM from LDS (R8-proven) with swizzled B-frag reads.
// ---------------------------------------------------------------------------
__global__ __launch_bounds__(256) void deform_tile_k(
    const float* __restrict__ xT, const float* __restrict__ om,
    const ushort* __restrict__ Wt, float* __restrict__ out) {
  __shared__ uint  s_addr[288];            // [gk][px] NHWC base (pre-*128)
  __shared__ uint2 s_wq[288];              // 4 x f16 folded weights
  __shared__ uint  s_val[NKS * 16 * 16];   // 36864 B: [step][px][chunk-swz]

  int bid = blockIdx.x;
  int blk = (bid & 7) * 576 + (bid >> 3);  // bijective, 4608 % 8 == 0
  int pt = blk % 1152, b = blk / 1152;
  int ho = pt / 12, wo0 = (pt % 12) * 16;
  int tid = threadIdx.x;

  // ---- phase 0: canonical in-bounds bilinear coefficients (proven math) ----
  for (int e = tid; e < 288; e += 256) {
    int px = e & 15, gk = e >> 4;
    int g = gk / 9, k = gk - g * 9;
    int wo = wo0 + px;
    const float* omb = om + (size_t)b * OMCH * HW + (size_t)ho * WO + wo;
    float offy = omb[(size_t)(g * 18 + k * 2 + 0) * HW];
    float offx = omb[(size_t)(g * 18 + k * 2 + 1) * HW];
    float z    = omb[(size_t)(36 + g * 9 + k) * HW];
    float msk  = 2.f / (1.f + __expf(-z));
    float py = (float)(ho - 2 + (k / 3) * 2) + offy;
    float px_ = (float)(wo - 2 + (k % 3) * 2) + offx;
    float y0f = floorf(py), x0f = floorf(px_);
    int   y0 = (int)y0f, x0 = (int)x0f;
    float ty = py - y0f, tx = px_ - x0f;
    float wy0 = (y0 >= 0 && y0 < H_)      ? (1.f - ty) : 0.f;
    float wy1 = (y0 >= -1 && y0 < H_ - 1) ? ty         : 0.f;
    float wx0 = (x0 >= 0 && x0 < W_)      ? (1.f - tx) : 0.f;
    float wx1 = (x0 >= -1 && x0 < W_ - 1) ? tx         : 0.f;
    int yb  = min(max(y0, 0), H_ - 2);
    int xb_ = min(max(x0, 0), W_ - 2);
    float wAy = (y0 == yb      ? wy0 : 0.f) + (y0 + 1 == yb      ? wy1 : 0.f);
    float wBy = (y0 == yb + 1  ? wy0 : 0.f) + (y0 + 1 == yb + 1  ? wy1 : 0.f);
    float wAx = (x0 == xb_     ? wx0 : 0.f) + (x0 + 1 == xb_     ? wx1 : 0.f);
    float wBx = (x0 == xb_ + 1 ? wx0 : 0.f) + (x0 + 1 == xb_ + 1 ? wx1 : 0.f);
    s_addr[e] = (uint)((yb * W_ + xb_) * 128);
    union { __half2 h; uint u; } uA, uB;
    uA.h = __half2{__float2half(wAy * wAx * msk), __float2half(wAy * wBx * msk)};
    uB.h = __half2{__float2half(wBy * wAx * msk), __float2half(wBy * wBx * msk)};
    s_wq[e] = make_uint2(uA.u, uB.u);
  }
  __syncthreads();

  int lane = tid & 63, wv = tid >> 6;

  // ---- phase 1: 144 pair-tasks (36/wave), channel-lane coalesced ----
  {
    int half = lane >> 5, cl = lane & 31;
    const float* xTb = xT + (size_t)b * HW * 128;

    float2 A[4], Bv[4];
    float2 wAa, wBa, wAb, wBb;
    int rwA, cdA, rwB, cdB;

    auto load_t = [&](int t, float2 (&c)[4], float2& wAo, float2& wBo,
                      int& rowo, int& cido) {
      int gk = t >> 3, pp = t & 7;
      int px = 2 * pp + half;
      int ci = gk * 16 + px;
      uint base = s_addr[ci];
      uint2 wq = s_wq[ci];
      union { __half2 h; uint u; } uA, uB;
      uA.u = wq.x; uB.u = wq.y;
      wAo = __half22float2(uA.h);
      wBo = __half22float2(uB.h);
      int g = gk >= 9;
      const float* ptr = xTb + base + g * 64 + cl * 2;
      c[0] = *(const float2*)(ptr);                    // (y  , x  ) ch cl*2,+1
      c[1] = *(const float2*)(ptr + 128);              // (y  , x+1)
      c[2] = *(const float2*)(ptr + W_ * 128);         // (y+1, x  )
      c[3] = *(const float2*)(ptr + W_ * 128 + 128);   // (y+1, x+1)
      int k = gk - g * 9;
      int step = g * 18 + k * 2 + (cl >> 4);
      rowo = step * 16 + px;
      int j = cl & 15;
      cido = ((((j >> 2) ^ (px & 3)) << 2)) | (j & 3); // chunk-swizzled uint idx
    };

    auto fin_t = [&](const float2 (&c)[4], float2 wA, float2 wB,
                     int row, int cid) {
      float v0 = wA.x * c[0].x + wA.y * c[1].x + wB.x * c[2].x + wB.y * c[3].x;
      float v1 = wA.x * c[0].y + wA.y * c[1].y + wB.x * c[2].y + wB.y * c[3].y;
      s_val[row * 16 + cid] = (uint)f2bf(v0) | ((uint)f2bf(v1) << 16);
    };

    int t0 = wv * 36;
    load_t(t0, A, wAa, wBa, rwA, cdA);
    for (int i = 0; i < 34; i += 2) {
      load_t(t0 + i + 1, Bv, wAb, wBb, rwB, cdB);
      fin_t(A, wAa, wBa, rwA, cdA);
      load_t(t0 + i + 2, A, wAa, wBa, rwA, cdA);
      fin_t(Bv, wAb, wBb, rwB, cdB);
    }
    load_t(t0 + 35, Bv, wAb, wBb, rwB, cdB);
    fin_t(A, wAa, wBa, rwA, cdA);
    fin_t(Bv, wAb, wBb, rwB, cdB);
  }
  __syncthreads();

  // ---- phase 2: GEMM from LDS (swizzled B-frag reads) ----
  int col = lane & 15, oct = lane >> 4;

  const ushort* wb0 = Wt + (size_t)(wv * 32 + col) * RDIM + oct * 8;
  const ushort* wb1 = wb0 + (size_t)16 * RDIM;
  int swz = (oct ^ (col & 3)) << 2;

  f32x4 acc[2];
  acc[0] = (f32x4){0.f, 0.f, 0.f, 0.f};
  acc[1] = (f32x4){0.f, 0.f, 0.f, 0.f};

  bf16x8 a0_0 = *(const bf16x8*)(wb0);
  bf16x8 a1_0 = *(const bf16x8*)(wb1);
  bf16x8 a0_1 = *(const bf16x8*)(wb0 + 32);
  bf16x8 a1_1 = *(const bf16x8*)(wb1 + 32);

  for (int it2 = 0; it2 < NKS; it2 += 2) {
    {
      bf16x8 pa0 = a0_0, pa1 = a1_0;
      if (it2 + 2 < NKS) {
        a0_0 = *(const bf16x8*)(wb0 + (it2 + 2) * 32);
        a1_0 = *(const bf16x8*)(wb1 + (it2 + 2) * 32);
      }
      bf16x8 bfr = *(const bf16x8*)&s_val[(it2 * 16 + col) * 16 + swz];
      acc[0] = __builtin_amdgcn_mfma_f32_16x16x32_bf16(pa0, bfr, acc[0], 0, 0, 0);
      acc[1] = __builtin_amdgcn_mfma_f32_16x16x32_bf16(pa1, bfr, acc[1], 0, 0, 0);
    }
    {
      bf16x8 pa0 = a0_1, pa1 = a1_1;
      if (it2 + 3 < NKS) {
        a0_1 = *(const bf16x8*)(wb0 + (it2 + 3) * 32);
        a1_1 = *(const bf16x8*)(wb1 + (it2 + 3) * 32);
      }
      bf16x8 bfr = *(const bf16x8*)&s_val[((it2 + 1) * 16 + col) * 16 + swz];
      acc[0] = __builtin_amdgcn_mfma_f32_16x16x32_bf16(pa0, bfr, acc[0], 0, 0, 0);
      acc[1] = __builtin_amdgcn_mfma_f32_16x16x32_bf16(pa1, bfr, acc[1], 0, 0, 0);
    }
  }

#pragma unroll
  for (int m = 0; m < 2; ++m)
#pragma unroll
    for (int ri = 0; ri < 4; ++ri) {
      int o = wv * 32 + m * 16 + oct * 4 + ri;
      out[((size_t)(b * COUT + o) * HO + ho) * WO + wo0 + col] = acc[m][ri];
    }
}

// ---------------------------------------------------------------------------
extern "C" void kernel_launch(void* const* d_in, const int* in_sizes, int n_in,
                              void* d_out, int out_size, void* d_ws, size_t ws_size,
                              hipStream_t stream) {
  const float* x        = (const float*)d_in[0];
  const float* w_offset = (const float*)d_in[1];
  const float* b_offset = (const float*)d_in[2];
  const float* w_deform = (const float*)d_in[3];
  float* out = (float*)d_out;

  char* ws = (char*)d_ws;
  float*  om  = (float*)ws;                             // 15,925,248 B
  ushort* Wt  = (ushort*)(ws + 15925248);               //    294,912 B
  ushort* Awo = (ushort*)(ws + 15925248 + 294912);      //    147,456 B
  float*  xT  = (float*)(ws + 15925248 + 294912 + 147456);  // 37,748,736 B

  prep_k<<<576, 256, 0, stream>>>(w_deform, w_offset, Wt, Awo);
  xt_k<<<1152, 256, 0, stream>>>(x, xT);
  offset_mfma_k<<<1152, 256, 0, stream>>>(x, Awo, b_offset, om);
  deform_tile_k<<<4608, 256, 0, stream>>>(xT, om, Wt, out);
}

// Round 11
// 249.033 us; speedup vs baseline: 1.3630x; 1.1397x over previous
//
#include <hip/hip_runtime.h>
#include <hip/hip_fp16.h>
#include <math.h>

#define BB   4
#define C_   128
#define H_   96
#define W_   192
#define COUT 128
#define DG_  2
#define CG_  64
#define K_   9
#define HO   96
#define WO   192
#define HW   (H_ * W_)       // 18432
#define OMCH 54
#define RDIM (C_ * K_)       // 1152
#define NKS  (RDIM / 32)     // 36 K-steps

typedef __attribute__((ext_vector_type(8))) short bf16x8;
typedef __attribute__((ext_vector_type(4))) float f32x4;

static __device__ __forceinline__ ushort f2bf(float f) {
  union { float f; uint u; } v; v.f = f;
  uint r = v.u + 0x7fff + ((v.u >> 16) & 1);   // RNE
  return (ushort)(r >> 16);
}

// ---------------------------------------------------------------------------
// Prep: bf16 weights, k-major orderings (proven).
// ---------------------------------------------------------------------------
__global__ __launch_bounds__(256) void prep_k(
    const float* __restrict__ wd, const float* __restrict__ wo,
    ushort* __restrict__ Wt, ushort* __restrict__ Awo) {
  int i = blockIdx.x * 256 + threadIdx.x;
  if (i < 128 * RDIM) {
    int o = i / RDIM, r = i - o * RDIM;
    int g = r / 576, t = r - g * 576;
    int k = t >> 6, cg = t & 63;
    Wt[i] = f2bf(wd[((size_t)o * C_ + g * 64 + cg) * 9 + k]);
  }
  if (i < 64 * RDIM) {
    int o2 = i / RDIM, r = i - o2 * RDIM;
    int k = r >> 7, c = r & 127;
    int g = o2 >> 5, j = o2 & 31;
    float v = (((c >> 6) == g) && (j < 27))
                ? wo[(((size_t)(g * 27 + j)) * 64 + (c & 63)) * 9 + k] : 0.f;
    Awo[i] = f2bf(v);
  }
}

// ---------------------------------------------------------------------------
// NCHW -> NHWC fp16 transpose of x: xT[b][p][c] = (half)x[b][c][p].
// ---------------------------------------------------------------------------
__global__ __launch_bounds__(256) void xt_k(
    const float* __restrict__ x, __half* __restrict__ xT) {
  __shared__ float t[128][65];
  int blk = blockIdx.x;
  int b = blk / 288, p0 = (blk % 288) * 64;
  int q = threadIdx.x >> 6, l = threadIdx.x & 63;
  const float* xb = x + (size_t)b * C_ * HW;
#pragma unroll
  for (int it = 0; it < 32; ++it) {
    int c = q * 32 + it;
    t[c][l] = xb[(size_t)c * HW + p0 + l];
  }
  __syncthreads();
  uint* xTb = (uint*)(xT + (size_t)b * HW * 128);
#pragma unroll
  for (int it = 0; it < 16; ++it) {
    int px = q * 16 + it;
    union { __half2 h; uint u; } pk;
    pk.h = __half2{__float2half(t[2 * l][px]), __float2half(t[2 * l + 1][px])};
    xTb[(size_t)(p0 + px) * 64 + l] = pk.u;
  }
}

// ---------------------------------------------------------------------------
// Offset conv as MFMA (R3 exact — proven deterministic).
// ---------------------------------------------------------------------------
__global__ __launch_bounds__(256) void offset_mfma_k(
    const float* __restrict__ x, const ushort* __restrict__ Awo,
    const float* __restrict__ b_offset, float* __restrict__ om) {
  __shared__ uint s_val[2][64][20];

  int bid = blockIdx.x;
  int blk = (bid & 7) * 144 + (bid >> 3);
  int wt = blk % 3, bh = blk / 3;
  int ho = bh % HO, b = bh / HO;
  int wo0 = wt * 64;
  int lane = threadIdx.x & 63, wv = threadIdx.x >> 6;

  const float* xb = x + (size_t)b * C_ * HW;
  f32x4 acc[4];
#pragma unroll
  for (int n = 0; n < 4; ++n) acc[n] = (f32x4){0.f, 0.f, 0.f, 0.f};

  const ushort* abase = Awo + (size_t)(wv * 16 + (lane & 15)) * RDIM + (lane >> 4) * 8;

  float gv[8];

  auto patch_gather = [&](int step) {
    int k = step >> 2;
    int dy = k / 3, dx = k - dy * 3;
    int y  = ho - 2 + 2 * dy;
    int xc = wo0 + lane - 2 + 2 * dx;
    bool ok = (y >= 0) & (y < H_) & (xc >= 0) & (xc < W_);
    int c0 = (step & 3) * 32 + wv * 8;
    const float* pl = xb + ((ptrdiff_t)c0 * HW + y * W_ + xc);
#pragma unroll
    for (int j = 0; j < 8; ++j) { gv[j] = ok ? *pl : 0.f; pl += HW; }
  };

  auto patch_finish = [&](int nb) {
    uint res[4];
#pragma unroll
    for (int j = 0; j < 8; ++j) {
      uint bf = (uint)f2bf(gv[j]);
      if (j & 1) res[j >> 1] |= bf << 16; else res[j >> 1] = bf;
    }
    *(int4*)&s_val[nb][lane][wv * 4] = *(int4*)&res[0];
  };

  auto mfma_step = [&](int step, int cb) {
    bf16x8 af = *(const bf16x8*)(abase + step * 32);
#pragma unroll
    for (int n = 0; n < 4; ++n) {
      bf16x8 bfr = *(const bf16x8*)&s_val[cb][n * 16 + (lane & 15)][(lane >> 4) * 4];
      acc[n] = __builtin_amdgcn_mfma_f32_16x16x32_bf16(af, bfr, acc[n], 0, 0, 0);
    }
  };

  patch_gather(0);
  patch_finish(0);
  __syncthreads();
  for (int it = 0; it < NKS - 1; ++it) {
    patch_gather(it + 1);
    mfma_step(it, it & 1);
    patch_finish((it + 1) & 1);
    __syncthreads();
  }
  mfma_step(NKS - 1, (NKS - 1) & 1);

  int col = lane & 15, rgrp = lane >> 4;
#pragma unroll
  for (int n = 0; n < 4; ++n)
#pragma unroll
    for (int ri = 0; ri < 4; ++ri) {
      int o2 = wv * 16 + rgrp * 4 + ri;
      int g = o2 >> 5, j = o2 & 31;
      if (j < 27) {
        int ch = g * 27 + j;
        om[((size_t)(b * OMCH + ch) * HO + ho) * WO + wo0 + n * 16 + col] =
            acc[n][ri] + b_offset[ch];
      }
    }
}

// ---------------------------------------------------------------------------
// Tile-fused main kernel, fp16 NHWC gathers, quad-tasks.
// Block = 16 px x 128 Cout, 4608 blocks.
// Phase 1: task = (gk, px-quad); lane = (px-sub = l>>4, ch-quad = l&15).
//   4 x 8B f16 loads per lane; each wave-load = 4 contiguous 128 B regions
//   (8 lines). 72 tasks, 18/wave, depth-2 pipeline, no barriers.
// Phase 2: GEMM from LDS (R10-proven, swizzled B-frag reads).
// ---------------------------------------------------------------------------
__global__ __launch_bounds__(256) void deform_tile_k(
    const __half* __restrict__ xT, const float* __restrict__ om,
    const ushort* __restrict__ Wt, float* __restrict__ out) {
  __shared__ uint  s_addr[288];            // [gk][px] NHWC base (elem units, *128)
  __shared__ uint2 s_wq[288];              // 4 x f16 folded weights
  __shared__ uint  s_val[NKS * 16 * 16];   // 36864 B: [step][px][chunk-swz]

  int bid = blockIdx.x;
  int blk = (bid & 7) * 576 + (bid >> 3);  // bijective, 4608 % 8 == 0
  int pt = blk % 1152, b = blk / 1152;
  int ho = pt / 12, wo0 = (pt % 12) * 16;
  int tid = threadIdx.x;

  // ---- phase 0: canonical in-bounds bilinear coefficients (proven math) ----
  for (int e = tid; e < 288; e += 256) {
    int px = e & 15, gk = e >> 4;
    int g = gk / 9, k = gk - g * 9;
    int wo = wo0 + px;
    const float* omb = om + (size_t)b * OMCH * HW + (size_t)ho * WO + wo;
    float offy = omb[(size_t)(g * 18 + k * 2 + 0) * HW];
    float offx = omb[(size_t)(g * 18 + k * 2 + 1) * HW];
    float z    = omb[(size_t)(36 + g * 9 + k) * HW];
    float msk  = 2.f / (1.f + __expf(-z));
    float py = (float)(ho - 2 + (k / 3) * 2) + offy;
    float px_ = (float)(wo - 2 + (k % 3) * 2) + offx;
    float y0f = floorf(py), x0f = floorf(px_);
    int   y0 = (int)y0f, x0 = (int)x0f;
    float ty = py - y0f, tx = px_ - x0f;
    float wy0 = (y0 >= 0 && y0 < H_)      ? (1.f - ty) : 0.f;
    float wy1 = (y0 >= -1 && y0 < H_ - 1) ? ty         : 0.f;
    float wx0 = (x0 >= 0 && x0 < W_)      ? (1.f - tx) : 0.f;
    float wx1 = (x0 >= -1 && x0 < W_ - 1) ? tx         : 0.f;
    int yb  = min(max(y0, 0), H_ - 2);
    int xb_ = min(max(x0, 0), W_ - 2);
    float wAy = (y0 == yb      ? wy0 : 0.f) + (y0 + 1 == yb      ? wy1 : 0.f);
    float wBy = (y0 == yb + 1  ? wy0 : 0.f) + (y0 + 1 == yb + 1  ? wy1 : 0.f);
    float wAx = (x0 == xb_     ? wx0 : 0.f) + (x0 + 1 == xb_     ? wx1 : 0.f);
    float wBx = (x0 == xb_ + 1 ? wx0 : 0.f) + (x0 + 1 == xb_ + 1 ? wx1 : 0.f);
    s_addr[e] = (uint)((yb * W_ + xb_) * 128);
    union { __half2 h; uint u; } uA, uB;
    uA.h = __half2{__float2half(wAy * wAx * msk), __float2half(wAy * wBx * msk)};
    uB.h = __half2{__float2half(wBy * wAx * msk), __float2half(wBy * wBx * msk)};
    s_wq[e] = make_uint2(uA.u, uB.u);
  }
  __syncthreads();

  int lane = tid & 63, wv = tid >> 6;

  // ---- phase 1: 72 quad-tasks (18/wave), fp16 channel-lane coalesced ----
  {
    int pq = lane >> 4, q = lane & 15;
    const __half* xTb = xT + (size_t)b * HW * 128;

    uint2 A[4], Bv[4];
    float2 wAa, wBa, wAb, wBb;
    int rwA, cdA, rwB, cdB;

    auto load_t = [&](int t, uint2 (&c)[4], float2& wAo, float2& wBo,
                      int& rowo, int& cido) {
      int gk = t >> 2;
      int px = ((t & 3) << 2) | pq;
      int ci = gk * 16 + px;
      uint base = s_addr[ci];
      uint2 wq = s_wq[ci];
      union { __half2 h; uint u; } uA, uB;
      uA.u = wq.x; uB.u = wq.y;
      wAo = __half22float2(uA.h);
      wBo = __half22float2(uB.h);
      int g = gk >= 9;
      const __half* ptr = xTb + base + g * 64 + q * 4;
      c[0] = *(const uint2*)(ptr);                    // (y  , x  ) ch 4q..4q+3
      c[1] = *(const uint2*)(ptr + 128);              // (y  , x+1)
      c[2] = *(const uint2*)(ptr + W_ * 128);         // (y+1, x  )
      c[3] = *(const uint2*)(ptr + W_ * 128 + 128);   // (y+1, x+1)
      int k = gk - g * 9;
      int step = g * 18 + k * 2 + (q >> 3);
      rowo = step * 16 + px;
      int rq = q & 7;                                 // r-quad: r = 4rq..4rq+3
      int chunk = (rq >> 1) ^ (px & 3);               // swizzled chunk
      cido = (chunk << 2) | ((rq & 1) << 1);          // even uint index
    };

    auto fin_t = [&](const uint2 (&c)[4], float2 wA, float2 wB,
                     int row, int cid) {
      float2 c0a = __half22float2(*(const __half2*)&c[0].x);
      float2 c0b = __half22float2(*(const __half2*)&c[0].y);
      float2 c1a = __half22float2(*(const __half2*)&c[1].x);
      float2 c1b = __half22float2(*(const __half2*)&c[1].y);
      float2 c2a = __half22float2(*(const __half2*)&c[2].x);
      float2 c2b = __half22float2(*(const __half2*)&c[2].y);
      float2 c3a = __half22float2(*(const __half2*)&c[3].x);
      float2 c3b = __half22float2(*(const __half2*)&c[3].y);
      float v0 = wA.x * c0a.x + wA.y * c1a.x + wB.x * c2a.x + wB.y * c3a.x;
      float v1 = wA.x * c0a.y + wA.y * c1a.y + wB.x * c2a.y + wB.y * c3a.y;
      float v2 = wA.x * c0b.x + wA.y * c1b.x + wB.x * c2b.x + wB.y * c3b.x;
      float v3 = wA.x * c0b.y + wA.y * c1b.y + wB.x * c2b.y + wB.y * c3b.y;
      uint r0 = (uint)f2bf(v0) | ((uint)f2bf(v1) << 16);
      uint r1 = (uint)f2bf(v2) | ((uint)f2bf(v3) << 16);
      *(uint2*)&s_val[row * 16 + cid] = make_uint2(r0, r1);
    };

    int t0 = wv * 18;
    load_t(t0, A, wAa, wBa, rwA, cdA);
    for (int i = 0; i < 16; i += 2) {
      load_t(t0 + i + 1, Bv, wAb, wBb, rwB, cdB);
      fin_t(A, wAa, wBa, rwA, cdA);
      load_t(t0 + i + 2, A, wAa, wBa, rwA, cdA);
      fin_t(Bv, wAb, wBb, rwB, cdB);
    }
    load_t(t0 + 17, Bv, wAb, wBb, rwB, cdB);
    fin_t(A, wAa, wBa, rwA, cdA);
    fin_t(Bv, wAb, wBb, rwB, cdB);
  }
  __syncthreads();

  // ---- phase 2: GEMM from LDS (swizzled B-frag reads, R10-proven) ----
  int col = lane & 15, oct = lane >> 4;

  const ushort* wb0 = Wt + (size_t)(wv * 32 + col) * RDIM + oct * 8;
  const ushort* wb1 = wb0 + (size_t)16 * RDIM;
  int swz = (oct ^ (col & 3)) << 2;

  f32x4 acc[2];
  acc[0] = (f32x4){0.f, 0.f, 0.f, 0.f};
  acc[1] = (f32x4){0.f, 0.f, 0.f, 0.f};

  bf16x8 a0_0 = *(const bf16x8*)(wb0);
  bf16x8 a1_0 = *(const bf16x8*)(wb1);
  bf16x8 a0_1 = *(const bf16x8*)(wb0 + 32);
  bf16x8 a1_1 = *(const bf16x8*)(wb1 + 32);

  for (int it2 = 0; it2 < NKS; it2 += 2) {
    {
      bf16x8 pa0 = a0_0, pa1 = a1_0;
      if (it2 + 2 < NKS) {
        a0_0 = *(const bf16x8*)(wb0 + (it2 + 2) * 32);
        a1_0 = *(const bf16x8*)(wb1 + (it2 + 2) * 32);
      }
      bf16x8 bfr = *(const bf16x8*)&s_val[(it2 * 16 + col) * 16 + swz];
      acc[0] = __builtin_amdgcn_mfma_f32_16x16x32_bf16(pa0, bfr, acc[0], 0, 0, 0);
      acc[1] = __builtin_amdgcn_mfma_f32_16x16x32_bf16(pa1, bfr, acc[1], 0, 0, 0);
    }
    {
      bf16x8 pa0 = a0_1, pa1 = a1_1;
      if (it2 + 3 < NKS) {
        a0_1 = *(const bf16x8*)(wb0 + (it2 + 3) * 32);
        a1_1 = *(const bf16x8*)(wb1 + (it2 + 3) * 32);
      }
      bf16x8 bfr = *(const bf16x8*)&s_val[((it2 + 1) * 16 + col) * 16 + swz];
      acc[0] = __builtin_amdgcn_mfma_f32_16x16x32_bf16(pa0, bfr, acc[0], 0, 0, 0);
      acc[1] = __builtin_amdgcn_mfma_f32_16x16x32_bf16(pa1, bfr, acc[1], 0, 0, 0);
    }
  }

#pragma unroll
  for (int m = 0; m < 2; ++m)
#pragma unroll
    for (int ri = 0; ri < 4; ++ri) {
      int o = wv * 32 + m * 16 + oct * 4 + ri;
      out[((size_t)(b * COUT + o) * HO + ho) * WO + wo0 + col] = acc[m][ri];
    }
}

// ---------------------------------------------------------------------------
extern "C" void kernel_launch(void* const* d_in, const int* in_sizes, int n_in,
                              void* d_out, int out_size, void* d_ws, size_t ws_size,
                              hipStream_t stream) {
  const float* x        = (const float*)d_in[0];
  const float* w_offset = (const float*)d_in[1];
  const float* b_offset = (const float*)d_in[2];
  const float* w_deform = (const float*)d_in[3];
  float* out = (float*)d_out;

  char* ws = (char*)d_ws;
  float*  om  = (float*)ws;                             // 15,925,248 B
  ushort* Wt  = (ushort*)(ws + 15925248);               //    294,912 B
  ushort* Awo = (ushort*)(ws + 15925248 + 294912);      //    147,456 B
  __half* xT  = (__half*)(ws + 15925248 + 294912 + 147456);  // 18,874,368 B

  prep_k<<<576, 256, 0, stream>>>(w_deform, w_offset, Wt, Awo);
  xt_k<<<1152, 256, 0, stream>>>(x, xT);
  offset_mfma_k<<<1152, 256, 0, stream>>>(x, Awo, b_offset, om);
  deform_tile_k<<<4608, 256, 0, stream>>>(xT, om, Wt, out);
}

// Round 12
// 140.003 us; speedup vs baseline: 2.4244x; 1.7788x over previous
//
#include <hip/hip_runtime.h>
#include <hip/hip_fp16.h>
#include <math.h>

#define BB   4
#define C_   128
#define H_   96
#define W_   192
#define COUT 128
#define DG_  2
#define CG_  64
#define K_   9
#define HO   96
#define WO   192
#define HW   (H_ * W_)       // 18432
#define OMCH 54
#define RDIM (C_ * K_)       // 1152
#define NKS  (RDIM / 32)     // 36 K-steps

typedef __attribute__((ext_vector_type(8))) short bf16x8;
typedef __attribute__((ext_vector_type(4))) float f32x4;

static __device__ __forceinline__ ushort f2bf(float f) {
  union { float f; uint u; } v; v.f = f;
  uint r = v.u + 0x7fff + ((v.u >> 16) & 1);   // RNE
  return (ushort)(r >> 16);
}

// ---------------------------------------------------------------------------
// Prep: WtA = A-fragment-major bf16 weights; Awo = offset-conv A (proven).
//  WtA[(s*4+wv)*2+m][oct*16+colA][8j]: lane-contiguous 1KB per (s,wv,m).
//  element = wd[o= wv*32+m*16+colA][r = s*32+oct*8+j] with r=g*576+k*64+cg.
// ---------------------------------------------------------------------------
__global__ __launch_bounds__(256) void prep_k(
    const float* __restrict__ wd, const float* __restrict__ wo,
    ushort* __restrict__ WtA, ushort* __restrict__ Awo) {
  int i = blockIdx.x * 256 + threadIdx.x;
  if (i < 128 * RDIM) {
    int blkA = i >> 9, within = i & 511;
    int oct = within >> 7, colA = (within >> 3) & 15, j = within & 7;
    int m = blkA & 1, wvq = (blkA >> 1) & 3, s = blkA >> 3;
    int o = wvq * 32 + m * 16 + colA;
    int r = s * 32 + oct * 8 + j;
    int g = r / 576, t = r - g * 576;
    int k = t >> 6, cg = t & 63;
    WtA[i] = f2bf(wd[((size_t)o * C_ + g * 64 + cg) * 9 + k]);
  }
  if (i < 64 * RDIM) {
    int o2 = i / RDIM, r = i - o2 * RDIM;
    int k = r >> 7, c = r & 127;
    int g = o2 >> 5, j = o2 & 31;
    float v = (((c >> 6) == g) && (j < 27))
                ? wo[(((size_t)(g * 27 + j)) * 64 + (c & 63)) * 9 + k] : 0.f;
    Awo[i] = f2bf(v);
  }
}

// ---------------------------------------------------------------------------
// NCHW -> NHWC fp16 transpose of x (R11-proven).
// ---------------------------------------------------------------------------
__global__ __launch_bounds__(256) void xt_k(
    const float* __restrict__ x, __half* __restrict__ xT) {
  __shared__ float t[128][65];
  int blk = blockIdx.x;
  int b = blk / 288, p0 = (blk % 288) * 64;
  int q = threadIdx.x >> 6, l = threadIdx.x & 63;
  const float* xb = x + (size_t)b * C_ * HW;
#pragma unroll
  for (int it = 0; it < 32; ++it) {
    int c = q * 32 + it;
    t[c][l] = xb[(size_t)c * HW + p0 + l];
  }
  __syncthreads();
  uint* xTb = (uint*)(xT + (size_t)b * HW * 128);
#pragma unroll
  for (int it = 0; it < 16; ++it) {
    int px = q * 16 + it;
    union { __half2 h; uint u; } pk;
    pk.h = __half2{__float2half(t[2 * l][px]), __float2half(t[2 * l + 1][px])};
    xTb[(size_t)(p0 + px) * 64 + l] = pk.u;
  }
}

// ---------------------------------------------------------------------------
// Offset conv as MFMA (R3 exact — proven deterministic).
// ---------------------------------------------------------------------------
__global__ __launch_bounds__(256) void offset_mfma_k(
    const float* __restrict__ x, const ushort* __restrict__ Awo,
    const float* __restrict__ b_offset, float* __restrict__ om) {
  __shared__ uint s_val[2][64][20];

  int bid = blockIdx.x;
  int blk = (bid & 7) * 144 + (bid >> 3);
  int wt = blk % 3, bh = blk / 3;
  int ho = bh % HO, b = bh / HO;
  int wo0 = wt * 64;
  int lane = threadIdx.x & 63, wv = threadIdx.x >> 6;

  const float* xb = x + (size_t)b * C_ * HW;
  f32x4 acc[4];
#pragma unroll
  for (int n = 0; n < 4; ++n) acc[n] = (f32x4){0.f, 0.f, 0.f, 0.f};

  const ushort* abase = Awo + (size_t)(wv * 16 + (lane & 15)) * RDIM + (lane >> 4) * 8;

  float gv[8];

  auto patch_gather = [&](int step) {
    int k = step >> 2;
    int dy = k / 3, dx = k - dy * 3;
    int y  = ho - 2 + 2 * dy;
    int xc = wo0 + lane - 2 + 2 * dx;
    bool ok = (y >= 0) & (y < H_) & (xc >= 0) & (xc < W_);
    int c0 = (step & 3) * 32 + wv * 8;
    const float* pl = xb + ((ptrdiff_t)c0 * HW + y * W_ + xc);
#pragma unroll
    for (int j = 0; j < 8; ++j) { gv[j] = ok ? *pl : 0.f; pl += HW; }
  };

  auto patch_finish = [&](int nb) {
    uint res[4];
#pragma unroll
    for (int j = 0; j < 8; ++j) {
      uint bf = (uint)f2bf(gv[j]);
      if (j & 1) res[j >> 1] |= bf << 16; else res[j >> 1] = bf;
    }
    *(int4*)&s_val[nb][lane][wv * 4] = *(int4*)&res[0];
  };

  auto mfma_step = [&](int step, int cb) {
    bf16x8 af = *(const bf16x8*)(abase + step * 32);
#pragma unroll
    for (int n = 0; n < 4; ++n) {
      bf16x8 bfr = *(const bf16x8*)&s_val[cb][n * 16 + (lane & 15)][(lane >> 4) * 4];
      acc[n] = __builtin_amdgcn_mfma_f32_16x16x32_bf16(af, bfr, acc[n], 0, 0, 0);
    }
  };

  patch_gather(0);
  patch_finish(0);
  __syncthreads();
  for (int it = 0; it < NKS - 1; ++it) {
    patch_gather(it + 1);
    mfma_step(it, it & 1);
    patch_finish((it + 1) & 1);
    __syncthreads();
  }
  mfma_step(NKS - 1, (NKS - 1) & 1);

  int col = lane & 15, rgrp = lane >> 4;
#pragma unroll
  for (int n = 0; n < 4; ++n)
#pragma unroll
    for (int ri = 0; ri < 4; ++ri) {
      int o2 = wv * 16 + rgrp * 4 + ri;
      int g = o2 >> 5, j = o2 & 31;
      if (j < 27) {
        int ch = g * 27 + j;
        om[((size_t)(b * OMCH + ch) * HO + ho) * WO + wo0 + n * 16 + col] =
            acc[n][ri] + b_offset[ch];
      }
    }
}

// ---------------------------------------------------------------------------
// Main kernel: 64 px x 128 Cout, 1152 blocks, K in 6 chunks of 192 r.
// Per chunk per wave: issue 24 coalesced 16B gather loads (6 tasks x 4
// corners) -> 48 MFMA with coalesced A (WtA frag-major) -> fin into LDS
// (balanced XOR swizzle) -> ONE barrier. Double-buffered 24KB chunk bufs.
// ---------------------------------------------------------------------------
__global__ __launch_bounds__(256, 2) void deform_main_k(
    const __half* __restrict__ xT, const float* __restrict__ om,
    const ushort* __restrict__ WtA, float* __restrict__ out) {
  __shared__ uint  s_addr[18 * 64];          // 4608 B: (yb*W+xb)*128 half-units
  __shared__ uint2 s_wq[18 * 64];            // 9216 B
  __shared__ uint  s_val[2][6 * 64 * 16];    // 2 x 24576 B chunk buffers

  int bid = blockIdx.x;
  int blk = (bid & 7) * 144 + (bid >> 3);    // bijective, 1152 % 8 == 0
  int wt = blk % 3, bh = blk / 3;
  int ho = bh % HO, b = bh / HO;
  int wo0 = wt * 64;
  int tid = threadIdx.x;
  int lane = tid & 63, wv = tid >> 6;

  // ---- phase 0: canonical in-bounds bilinear coefficients (proven math) ----
  for (int e = tid; e < 18 * 64; e += 256) {
    int px = e & 63, gk = e >> 6;
    int g = gk / 9, k = gk - g * 9;
    int wo = wo0 + px;
    const float* omb = om + (size_t)b * OMCH * HW + (size_t)ho * WO + wo;
    float offy = omb[(size_t)(g * 18 + k * 2 + 0) * HW];
    float offx = omb[(size_t)(g * 18 + k * 2 + 1) * HW];
    float z    = omb[(size_t)(36 + g * 9 + k) * HW];
    float msk  = 2.f / (1.f + __expf(-z));
    float py = (float)(ho - 2 + (k / 3) * 2) + offy;
    float px_ = (float)(wo - 2 + (k % 3) * 2) + offx;
    float y0f = floorf(py), x0f = floorf(px_);
    int   y0 = (int)y0f, x0 = (int)x0f;
    float ty = py - y0f, tx = px_ - x0f;
    float wy0 = (y0 >= 0 && y0 < H_)      ? (1.f - ty) : 0.f;
    float wy1 = (y0 >= -1 && y0 < H_ - 1) ? ty         : 0.f;
    float wx0 = (x0 >= 0 && x0 < W_)      ? (1.f - tx) : 0.f;
    float wx1 = (x0 >= -1 && x0 < W_ - 1) ? tx         : 0.f;
    int yb  = min(max(y0, 0), H_ - 2);
    int xb_ = min(max(x0, 0), W_ - 2);
    float wAy = (y0 == yb      ? wy0 : 0.f) + (y0 + 1 == yb      ? wy1 : 0.f);
    float wBy = (y0 == yb + 1  ? wy0 : 0.f) + (y0 + 1 == yb + 1  ? wy1 : 0.f);
    float wAx = (x0 == xb_     ? wx0 : 0.f) + (x0 + 1 == xb_     ? wx1 : 0.f);
    float wBx = (x0 == xb_ + 1 ? wx0 : 0.f) + (x0 + 1 == xb_ + 1 ? wx1 : 0.f);
    s_addr[e] = (uint)((yb * W_ + xb_) * 128);
    union { __half2 h; uint u; } uA, uB;
    uA.h = __half2{__float2half(wAy * wAx * msk), __float2half(wAy * wBx * msk)};
    uB.h = __half2{__float2half(wBy * wAx * msk), __float2half(wBy * wBx * msk)};
    s_wq[e] = make_uint2(uA.u, uB.u);
  }

  const __half* xTb = xT + (size_t)b * HW * 128;
  int sub = lane >> 3, q = lane & 7;     // px-sub(8), ch-oct(8)
  int col = lane & 15, oct = lane >> 4;  // GEMM lane roles

  f32x4 acc[2][4];
#pragma unroll
  for (int m = 0; m < 2; ++m)
#pragma unroll
    for (int n = 0; n < 4; ++n) acc[m][n] = (f32x4){0.f, 0.f, 0.f, 0.f};

  // per-task state for one chunk (6 tasks, statically indexed)
  uint4 C0[6], C1[6], C2[6], C3[6];
  uint2 WQ[6];
  int   IX[6];

  // issue all 24 gather loads of chunk c (lane covers 8 ch of one px)
  auto issue_chunk = [&](int c) {
#pragma unroll
    for (int t = 0; t < 6; ++t) {
      int idx = wv * 6 + t;              // 0..23
      int gkl = idx >> 3, po = idx & 7;
      int gk = c * 3 + gkl;
      int px = po * 8 + sub;
      int ci = gk * 64 + px;
      uint base = s_addr[ci];
      WQ[t] = s_wq[ci];
      int g = gk >= 9;
      const __half* p = xTb + base + g * 64 + q * 8;
      C0[t] = *(const uint4*)(p);
      C1[t] = *(const uint4*)(p + 128);
      C2[t] = *(const uint4*)(p + W_ * 128);
      C3[t] = *(const uint4*)(p + W_ * 128 + 128);
      int k = gk - 9 * g;
      int step = g * 18 + k * 2 + (q >> 2);
      int row = (step - c * 6) * 64 + px;
      IX[t] = row * 16 + (((q & 3) ^ (px & 3)) << 2);
    }
  };

  // combine + pack + LDS-write all 6 tasks into buffer nb
  auto finish_chunk = [&](int nb) {
#pragma unroll
    for (int t = 0; t < 6; ++t) {
      union { __half2 h; uint u; } uA, uB;
      uA.u = WQ[t].x; uB.u = WQ[t].y;
      float2 wA = __half22float2(uA.h);
      float2 wB = __half22float2(uB.h);
      uint res[4];
      const uint* a = (const uint*)&C0[t];
      const uint* b1 = (const uint*)&C1[t];
      const uint* c2 = (const uint*)&C2[t];
      const uint* d = (const uint*)&C3[t];
#pragma unroll
      for (int h = 0; h < 4; ++h) {
        float2 p0 = __half22float2(*(const __half2*)&a[h]);
        float2 p1 = __half22float2(*(const __half2*)&b1[h]);
        float2 p2 = __half22float2(*(const __half2*)&c2[h]);
        float2 p3 = __half22float2(*(const __half2*)&d[h]);
        float v0 = wA.x * p0.x + wA.y * p1.x + wB.x * p2.x + wB.y * p3.x;
        float v1 = wA.x * p0.y + wA.y * p1.y + wB.x * p2.y + wB.y * p3.y;
        res[h] = (uint)f2bf(v0) | ((uint)f2bf(v1) << 16);
      }
      *(uint4*)&s_val[nb][IX[t]] = make_uint4(res[0], res[1], res[2], res[3]);
    }
  };

  // 48 MFMA of chunk c from buffer cb, A coalesced from WtA
  auto mfma_chunk = [&](int c, int cb) {
#pragma unroll
    for (int ls = 0; ls < 6; ++ls) {
      int s = c * 6 + ls;
      const ushort* ab = WtA + (size_t)((s * 4 + wv) * 2) * 512 + (oct * 16 + col) * 8;
      bf16x8 a0 = *(const bf16x8*)(ab);
      bf16x8 a1 = *(const bf16x8*)(ab + 512);
#pragma unroll
      for (int n = 0; n < 4; ++n) {
        bf16x8 bfr = *(const bf16x8*)
            &s_val[cb][(ls * 64 + n * 16 + col) * 16 + ((oct ^ (col & 3)) << 2)];
        acc[0][n] = __builtin_amdgcn_mfma_f32_16x16x32_bf16(a0, bfr, acc[0][n], 0, 0, 0);
        acc[1][n] = __builtin_amdgcn_mfma_f32_16x16x32_bf16(a1, bfr, acc[1][n], 0, 0, 0);
      }
    }
  };

  __syncthreads();                  // coeffs ready
  issue_chunk(0);
  finish_chunk(0);
  __syncthreads();                  // buf0 ready

  for (int c = 0; c < 6; ++c) {
    if (c < 5) issue_chunk(c + 1);  // loads in flight across the MFMA block
    mfma_chunk(c, c & 1);
    if (c < 5) finish_chunk((c + 1) & 1);
    __syncthreads();
  }

  // ---- epilogue: C/D col=lane&15 (px), row=oct*4+reg (Cout) ----
#pragma unroll
  for (int m = 0; m < 2; ++m)
#pragma unroll
    for (int n = 0; n < 4; ++n)
#pragma unroll
      for (int ri = 0; ri < 4; ++ri) {
        int o = wv * 32 + m * 16 + oct * 4 + ri;
        out[((size_t)(b * COUT + o) * HO + ho) * WO + wo0 + n * 16 + col] = acc[m][n][ri];
      }
}

// ---------------------------------------------------------------------------
extern "C" void kernel_launch(void* const* d_in, const int* in_sizes, int n_in,
                              void* d_out, int out_size, void* d_ws, size_t ws_size,
                              hipStream_t stream) {
  const float* x        = (const float*)d_in[0];
  const float* w_offset = (const float*)d_in[1];
  const float* b_offset = (const float*)d_in[2];
  const float* w_deform = (const float*)d_in[3];
  float* out = (float*)d_out;

  char* ws = (char*)d_ws;
  float*  om  = (float*)ws;                             // 15,925,248 B
  ushort* WtA = (ushort*)(ws + 15925248);               //    294,912 B
  ushort* Awo = (ushort*)(ws + 15925248 + 294912);      //    147,456 B
  __half* xT  = (__half*)(ws + 15925248 + 294912 + 147456);  // 18,874,368 B

  prep_k<<<576, 256, 0, stream>>>(w_deform, w_offset, WtA, Awo);
  xt_k<<<1152, 256, 0, stream>>>(x, xT);
  offset_mfma_k<<<1152, 256, 0, stream>>>(x, Awo, b_offset, om);
  deform_main_k<<<1152, 256, 0, stream>>>(xT, om, WtA, out);
}

// Round 13
// 128.075 us; speedup vs baseline: 2.6502x; 1.0931x over previous
//
#include <hip/hip_runtime.h>
#include <hip/hip_fp16.h>
#include <math.h>

#define BB   4
#define C_   128
#define H_   96
#define W_   192
#define COUT 128
#define DG_  2
#define CG_  64
#define K_   9
#define HO   96
#define WO   192
#define HW   (H_ * W_)       // 18432
#define OMCH 54
#define RDIM (C_ * K_)       // 1152
#define NKS  (RDIM / 32)     // 36 K-steps

typedef __attribute__((ext_vector_type(8))) short bf16x8;
typedef __attribute__((ext_vector_type(8))) _Float16 f16x8;
typedef __attribute__((ext_vector_type(4))) float f32x4;

static __device__ __forceinline__ ushort f2bf(float f) {
  union { float f; uint u; } v; v.f = f;
  uint r = v.u + 0x7fff + ((v.u >> 16) & 1);   // RNE
  return (ushort)(r >> 16);
}

// ---------------------------------------------------------------------------
// Prep: WtA = A-fragment-major **f16** weights (layout R12-proven);
//       Awo = offset-conv bf16 A (proven).
// ---------------------------------------------------------------------------
__global__ __launch_bounds__(256) void prep_k(
    const float* __restrict__ wd, const float* __restrict__ wo,
    ushort* __restrict__ WtA, ushort* __restrict__ Awo) {
  int i = blockIdx.x * 256 + threadIdx.x;
  if (i < 128 * RDIM) {
    int blkA = i >> 9, within = i & 511;
    int oct = within >> 7, colA = (within >> 3) & 15, j = within & 7;
    int m = blkA & 1, wvq = (blkA >> 1) & 3, s = blkA >> 3;
    int o = wvq * 32 + m * 16 + colA;
    int r = s * 32 + oct * 8 + j;
    int g = r / 576, t = r - g * 576;
    int k = t >> 6, cg = t & 63;
    WtA[i] = __half_as_ushort(__float2half(wd[((size_t)o * C_ + g * 64 + cg) * 9 + k]));
  }
  if (i < 64 * RDIM) {
    int o2 = i / RDIM, r = i - o2 * RDIM;
    int k = r >> 7, c = r & 127;
    int g = o2 >> 5, j = o2 & 31;
    float v = (((c >> 6) == g) && (j < 27))
                ? wo[(((size_t)(g * 27 + j)) * 64 + (c & 63)) * 9 + k] : 0.f;
    Awo[i] = f2bf(v);
  }
}

// ---------------------------------------------------------------------------
// NCHW -> NHWC fp16 transpose of x (R11-proven).
// ---------------------------------------------------------------------------
__global__ __launch_bounds__(256) void xt_k(
    const float* __restrict__ x, __half* __restrict__ xT) {
  __shared__ float t[128][65];
  int blk = blockIdx.x;
  int b = blk / 288, p0 = (blk % 288) * 64;
  int q = threadIdx.x >> 6, l = threadIdx.x & 63;
  const float* xb = x + (size_t)b * C_ * HW;
#pragma unroll
  for (int it = 0; it < 32; ++it) {
    int c = q * 32 + it;
    t[c][l] = xb[(size_t)c * HW + p0 + l];
  }
  __syncthreads();
  uint* xTb = (uint*)(xT + (size_t)b * HW * 128);
#pragma unroll
  for (int it = 0; it < 16; ++it) {
    int px = q * 16 + it;
    union { __half2 h; uint u; } pk;
    pk.h = __half2{__float2half(t[2 * l][px]), __float2half(t[2 * l + 1][px])};
    xTb[(size_t)(p0 + px) * 64 + l] = pk.u;
  }
}

// ---------------------------------------------------------------------------
// Offset conv as MFMA (R3 exact — proven deterministic).
// ---------------------------------------------------------------------------
__global__ __launch_bounds__(256) void offset_mfma_k(
    const float* __restrict__ x, const ushort* __restrict__ Awo,
    const float* __restrict__ b_offset, float* __restrict__ om) {
  __shared__ uint s_val[2][64][20];

  int bid = blockIdx.x;
  int blk = (bid & 7) * 144 + (bid >> 3);
  int wt = blk % 3, bh = blk / 3;
  int ho = bh % HO, b = bh / HO;
  int wo0 = wt * 64;
  int lane = threadIdx.x & 63, wv = threadIdx.x >> 6;

  const float* xb = x + (size_t)b * C_ * HW;
  f32x4 acc[4];
#pragma unroll
  for (int n = 0; n < 4; ++n) acc[n] = (f32x4){0.f, 0.f, 0.f, 0.f};

  const ushort* abase = Awo + (size_t)(wv * 16 + (lane & 15)) * RDIM + (lane >> 4) * 8;

  float gv[8];

  auto patch_gather = [&](int step) {
    int k = step >> 2;
    int dy = k / 3, dx = k - dy * 3;
    int y  = ho - 2 + 2 * dy;
    int xc = wo0 + lane - 2 + 2 * dx;
    bool ok = (y >= 0) & (y < H_) & (xc >= 0) & (xc < W_);
    int c0 = (step & 3) * 32 + wv * 8;
    const float* pl = xb + ((ptrdiff_t)c0 * HW + y * W_ + xc);
#pragma unroll
    for (int j = 0; j < 8; ++j) { gv[j] = ok ? *pl : 0.f; pl += HW; }
  };

  auto patch_finish = [&](int nb) {
    uint res[4];
#pragma unroll
    for (int j = 0; j < 8; ++j) {
      uint bf = (uint)f2bf(gv[j]);
      if (j & 1) res[j >> 1] |= bf << 16; else res[j >> 1] = bf;
    }
    *(int4*)&s_val[nb][lane][wv * 4] = *(int4*)&res[0];
  };

  auto mfma_step = [&](int step, int cb) {
    bf16x8 af = *(const bf16x8*)(abase + step * 32);
#pragma unroll
    for (int n = 0; n < 4; ++n) {
      bf16x8 bfr = *(const bf16x8*)&s_val[cb][n * 16 + (lane & 15)][(lane >> 4) * 4];
      acc[n] = __builtin_amdgcn_mfma_f32_16x16x32_bf16(af, bfr, acc[n], 0, 0, 0);
    }
  };

  patch_gather(0);
  patch_finish(0);
  __syncthreads();
  for (int it = 0; it < NKS - 1; ++it) {
    patch_gather(it + 1);
    mfma_step(it, it & 1);
    patch_finish((it + 1) & 1);
    __syncthreads();
  }
  mfma_step(NKS - 1, (NKS - 1) & 1);

  int col = lane & 15, rgrp = lane >> 4;
#pragma unroll
  for (int n = 0; n < 4; ++n)
#pragma unroll
    for (int ri = 0; ri < 4; ++ri) {
      int o2 = wv * 16 + rgrp * 4 + ri;
      int g = o2 >> 5, j = o2 & 31;
      if (j < 27) {
        int ch = g * 27 + j;
        om[((size_t)(b * OMCH + ch) * HO + ho) * WO + wo0 + n * 16 + col] =
            acc[n][ri] + b_offset[ch];
      }
    }
}

// ---------------------------------------------------------------------------
// Main kernel (R12 structure, f16 math): 64 px x 128 Cout, 1152 blocks,
// K in 6 chunks of 192 r, double-buffered LDS, ONE barrier per chunk.
// finish = packed __hfma2 bilinear (4 ops / 2 samples, no cvt, no repack).
// MFMA = mfma_f32_16x16x32_f16.
// ---------------------------------------------------------------------------
__global__ __launch_bounds__(256, 2) void deform_main_k(
    const __half* __restrict__ xT, const float* __restrict__ om,
    const ushort* __restrict__ WtA, float* __restrict__ out) {
  __shared__ uint  s_addr[18 * 64];          // 4608 B
  __shared__ uint2 s_wq[18 * 64];            // 9216 B
  __shared__ uint  s_val[2][6 * 64 * 16];    // 2 x 24576 B chunk buffers

  int bid = blockIdx.x;
  int blk = (bid & 7) * 144 + (bid >> 3);    // bijective, 1152 % 8 == 0
  int wt = blk % 3, bh = blk / 3;
  int ho = bh % HO, b = bh / HO;
  int wo0 = wt * 64;
  int tid = threadIdx.x;
  int lane = tid & 63, wv = tid >> 6;

  // ---- phase 0: canonical in-bounds bilinear coefficients (proven math) ----
  for (int e = tid; e < 18 * 64; e += 256) {
    int px = e & 63, gk = e >> 6;
    int g = gk / 9, k = gk - g * 9;
    int wo = wo0 + px;
    const float* omb = om + (size_t)b * OMCH * HW + (size_t)ho * WO + wo;
    float offy = omb[(size_t)(g * 18 + k * 2 + 0) * HW];
    float offx = omb[(size_t)(g * 18 + k * 2 + 1) * HW];
    float z    = omb[(size_t)(36 + g * 9 + k) * HW];
    float msk  = 2.f / (1.f + __expf(-z));
    float py = (float)(ho - 2 + (k / 3) * 2) + offy;
    float px_ = (float)(wo - 2 + (k % 3) * 2) + offx;
    float y0f = floorf(py), x0f = floorf(px_);
    int   y0 = (int)y0f, x0 = (int)x0f;
    float ty = py - y0f, tx = px_ - x0f;
    float wy0 = (y0 >= 0 && y0 < H_)      ? (1.f - ty) : 0.f;
    float wy1 = (y0 >= -1 && y0 < H_ - 1) ? ty         : 0.f;
    float wx0 = (x0 >= 0 && x0 < W_)      ? (1.f - tx) : 0.f;
    float wx1 = (x0 >= -1 && x0 < W_ - 1) ? tx         : 0.f;
    int yb  = min(max(y0, 0), H_ - 2);
    int xb_ = min(max(x0, 0), W_ - 2);
    float wAy = (y0 == yb      ? wy0 : 0.f) + (y0 + 1 == yb      ? wy1 : 0.f);
    float wBy = (y0 == yb + 1  ? wy0 : 0.f) + (y0 + 1 == yb + 1  ? wy1 : 0.f);
    float wAx = (x0 == xb_     ? wx0 : 0.f) + (x0 + 1 == xb_     ? wx1 : 0.f);
    float wBx = (x0 == xb_ + 1 ? wx0 : 0.f) + (x0 + 1 == xb_ + 1 ? wx1 : 0.f);
    s_addr[e] = (uint)((yb * W_ + xb_) * 128);
    union { __half2 h; uint u; } uA, uB;
    uA.h = __half2{__float2half(wAy * wAx * msk), __float2half(wAy * wBx * msk)};
    uB.h = __half2{__float2half(wBy * wAx * msk), __float2half(wBy * wBx * msk)};
    s_wq[e] = make_uint2(uA.u, uB.u);
  }

  const __half* xTb = xT + (size_t)b * HW * 128;
  int sub = lane >> 3, q = lane & 7;     // px-sub(8), ch-oct(8)
  int col = lane & 15, oct = lane >> 4;  // GEMM lane roles

  f32x4 acc[2][4];
#pragma unroll
  for (int m = 0; m < 2; ++m)
#pragma unroll
    for (int n = 0; n < 4; ++n) acc[m][n] = (f32x4){0.f, 0.f, 0.f, 0.f};

  // per-task state for one chunk (6 tasks, statically indexed)
  uint4 C0[6], C1[6], C2[6], C3[6];
  uint2 WQ[6];
  int   IX[6];

  auto issue_chunk = [&](int c) {
#pragma unroll
    for (int t = 0; t < 6; ++t) {
      int idx = wv * 6 + t;              // 0..23
      int gkl = idx >> 3, po = idx & 7;
      int gk = c * 3 + gkl;
      int px = po * 8 + sub;
      int ci = gk * 64 + px;
      uint base = s_addr[ci];
      WQ[t] = s_wq[ci];
      int g = gk >= 9;
      const __half* p = xTb + base + g * 64 + q * 8;
      C0[t] = *(const uint4*)(p);
      C1[t] = *(const uint4*)(p + 128);
      C2[t] = *(const uint4*)(p + W_ * 128);
      C3[t] = *(const uint4*)(p + W_ * 128 + 128);
      int k = gk - 9 * g;
      int step = g * 18 + k * 2 + (q >> 2);
      int row = (step - c * 6) * 64 + px;
      IX[t] = row * 16 + (((q & 3) ^ (px & 3)) << 2);
    }
  };

  // packed-f16 bilinear combine + LDS write (values stored as f16)
  auto finish_chunk = [&](int nb) {
#pragma unroll
    for (int t = 0; t < 6; ++t) {
      union { __half2 h; uint u; } w0, w1;
      w0.u = WQ[t].x; w1.u = WQ[t].y;
      __half2 wAx = __low2half2(w0.h), wAy = __high2half2(w0.h);
      __half2 wBx = __low2half2(w1.h), wBy = __high2half2(w1.h);
      uint res[4];
      const uint* a  = (const uint*)&C0[t];
      const uint* b1 = (const uint*)&C1[t];
      const uint* c2 = (const uint*)&C2[t];
      const uint* d  = (const uint*)&C3[t];
#pragma unroll
      for (int h = 0; h < 4; ++h) {
        union { __half2 h2; uint u; } p0, p1, p2, p3, vv;
        p0.u = a[h]; p1.u = b1[h]; p2.u = c2[h]; p3.u = d[h];
        __half2 v = __hmul2(p0.h2, wAx);
        v = __hfma2(p1.h2, wAy, v);
        v = __hfma2(p2.h2, wBx, v);
        v = __hfma2(p3.h2, wBy, v);
        vv.h2 = v;
        res[h] = vv.u;
      }
      *(uint4*)&s_val[nb][IX[t]] = make_uint4(res[0], res[1], res[2], res[3]);
    }
  };

  auto mfma_chunk = [&](int c, int cb) {
#pragma unroll
    for (int ls = 0; ls < 6; ++ls) {
      int s = c * 6 + ls;
      const ushort* ab = WtA + (size_t)((s * 4 + wv) * 2) * 512 + (oct * 16 + col) * 8;
      f16x8 a0 = *(const f16x8*)(ab);
      f16x8 a1 = *(const f16x8*)(ab + 512);
#pragma unroll
      for (int n = 0; n < 4; ++n) {
        f16x8 bfr = *(const f16x8*)
            &s_val[cb][(ls * 64 + n * 16 + col) * 16 + ((oct ^ (col & 3)) << 2)];
        acc[0][n] = __builtin_amdgcn_mfma_f32_16x16x32_f16(a0, bfr, acc[0][n], 0, 0, 0);
        acc[1][n] = __builtin_amdgcn_mfma_f32_16x16x32_f16(a1, bfr, acc[1][n], 0, 0, 0);
      }
    }
  };

  __syncthreads();                  // coeffs ready
  issue_chunk(0);
  finish_chunk(0);
  __syncthreads();                  // buf0 ready

  for (int c = 0; c < 6; ++c) {
    if (c < 5) issue_chunk(c + 1);  // loads in flight across the MFMA block
    mfma_chunk(c, c & 1);
    if (c < 5) finish_chunk((c + 1) & 1);
    __syncthreads();
  }

  // ---- epilogue: C/D col=lane&15 (px), row=oct*4+reg (Cout) ----
#pragma unroll
  for (int m = 0; m < 2; ++m)
#pragma unroll
    for (int n = 0; n < 4; ++n)
#pragma unroll
      for (int ri = 0; ri < 4; ++ri) {
        int o = wv * 32 + m * 16 + oct * 4 + ri;
        out[((size_t)(b * COUT + o) * HO + ho) * WO + wo0 + n * 16 + col] = acc[m][n][ri];
      }
}

// ---------------------------------------------------------------------------
extern "C" void kernel_launch(void* const* d_in, const int* in_sizes, int n_in,
                              void* d_out, int out_size, void* d_ws, size_t ws_size,
                              hipStream_t stream) {
  const float* x        = (const float*)d_in[0];
  const float* w_offset = (const float*)d_in[1];
  const float* b_offset = (const float*)d_in[2];
  const float* w_deform = (const float*)d_in[3];
  float* out = (float*)d_out;

  char* ws = (char*)d_ws;
  float*  om  = (float*)ws;                             // 15,925,248 B
  ushort* WtA = (ushort*)(ws + 15925248);               //    294,912 B
  ushort* Awo = (ushort*)(ws + 15925248 + 294912);      //    147,456 B
  __half* xT  = (__half*)(ws + 15925248 + 294912 + 147456);  // 18,874,368 B

  prep_k<<<576, 256, 0, stream>>>(w_deform, w_offset, WtA, Awo);
  xt_k<<<1152, 256, 0, stream>>>(x, xT);
  offset_mfma_k<<<1152, 256, 0, stream>>>(x, Awo, b_offset, om);
  deform_main_k<<<1152, 256, 0, stream>>>(xT, om, WtA, out);
}

// Round 14
// 112.046 us; speedup vs baseline: 3.0293x; 1.1431x over previous
//
#include <hip/hip_runtime.h>
#include <hip/hip_fp16.h>
#include <math.h>

#define BB   4
#define C_   128
#define H_   96
#define W_   192
#define COUT 128
#define DG_  2
#define CG_  64
#define K_   9
#define HO   96
#define WO   192
#define HW   (H_ * W_)       // 18432
#define OMCH 54
#define RDIM (C_ * K_)       // 1152
#define NKS  (RDIM / 32)     // 36 K-steps
#define CSTEP 4              // K-steps per chunk
#define NCH  (NKS / CSTEP)   // 9 chunks
#define VROW 18              // padded uints per val row (bank-walk stride)

typedef __attribute__((ext_vector_type(8))) short bf16x8;
typedef __attribute__((ext_vector_type(8))) _Float16 f16x8;
typedef __attribute__((ext_vector_type(4))) float f32x4;

static __device__ __forceinline__ ushort f2bf(float f) {
  union { float f; uint u; } v; v.f = f;
  uint r = v.u + 0x7fff + ((v.u >> 16) & 1);   // RNE
  return (ushort)(r >> 16);
}

// ---------------------------------------------------------------------------
// Prep: WtA = A-fragment-major f16 weights (R12-proven layout);
//       Awo = offset-conv bf16 A (proven).
// ---------------------------------------------------------------------------
__global__ __launch_bounds__(256) void prep_k(
    const float* __restrict__ wd, const float* __restrict__ wo,
    ushort* __restrict__ WtA, ushort* __restrict__ Awo) {
  int i = blockIdx.x * 256 + threadIdx.x;
  if (i < 128 * RDIM) {
    int blkA = i >> 9, within = i & 511;
    int oct = within >> 7, colA = (within >> 3) & 15, j = within & 7;
    int m = blkA & 1, wvq = (blkA >> 1) & 3, s = blkA >> 3;
    int o = wvq * 32 + m * 16 + colA;
    int r = s * 32 + oct * 8 + j;
    int g = r / 576, t = r - g * 576;
    int k = t >> 6, cg = t & 63;
    WtA[i] = __half_as_ushort(__float2half(wd[((size_t)o * C_ + g * 64 + cg) * 9 + k]));
  }
  if (i < 64 * RDIM) {
    int o2 = i / RDIM, r = i - o2 * RDIM;
    int k = r >> 7, c = r & 127;
    int g = o2 >> 5, j = o2 & 31;
    float v = (((c >> 6) == g) && (j < 27))
                ? wo[(((size_t)(g * 27 + j)) * 64 + (c & 63)) * 9 + k] : 0.f;
    Awo[i] = f2bf(v);
  }
}

// ---------------------------------------------------------------------------
// NCHW -> NHWC fp16 transpose of x (R11-proven).
// ---------------------------------------------------------------------------
__global__ __launch_bounds__(256) void xt_k(
    const float* __restrict__ x, __half* __restrict__ xT) {
  __shared__ float t[128][65];
  int blk = blockIdx.x;
  int b = blk / 288, p0 = (blk % 288) * 64;
  int q = threadIdx.x >> 6, l = threadIdx.x & 63;
  const float* xb = x + (size_t)b * C_ * HW;
#pragma unroll
  for (int it = 0; it < 32; ++it) {
    int c = q * 32 + it;
    t[c][l] = xb[(size_t)c * HW + p0 + l];
  }
  __syncthreads();
  uint* xTb = (uint*)(xT + (size_t)b * HW * 128);
#pragma unroll
  for (int it = 0; it < 16; ++it) {
    int px = q * 16 + it;
    union { __half2 h; uint u; } pk;
    pk.h = __half2{__float2half(t[2 * l][px]), __float2half(t[2 * l + 1][px])};
    xTb[(size_t)(p0 + px) * 64 + l] = pk.u;
  }
}

// ---------------------------------------------------------------------------
// Offset conv as MFMA (R3 exact — proven deterministic).
// ---------------------------------------------------------------------------
__global__ __launch_bounds__(256) void offset_mfma_k(
    const float* __restrict__ x, const ushort* __restrict__ Awo,
    const float* __restrict__ b_offset, float* __restrict__ om) {
  __shared__ uint s_val[2][64][20];

  int bid = blockIdx.x;
  int blk = (bid & 7) * 144 + (bid >> 3);
  int wt = blk % 3, bh = blk / 3;
  int ho = bh % HO, b = bh / HO;
  int wo0 = wt * 64;
  int lane = threadIdx.x & 63, wv = threadIdx.x >> 6;

  const float* xb = x + (size_t)b * C_ * HW;
  f32x4 acc[4];
#pragma unroll
  for (int n = 0; n < 4; ++n) acc[n] = (f32x4){0.f, 0.f, 0.f, 0.f};

  const ushort* abase = Awo + (size_t)(wv * 16 + (lane & 15)) * RDIM + (lane >> 4) * 8;

  float gv[8];

  auto patch_gather = [&](int step) {
    int k = step >> 2;
    int dy = k / 3, dx = k - dy * 3;
    int y  = ho - 2 + 2 * dy;
    int xc = wo0 + lane - 2 + 2 * dx;
    bool ok = (y >= 0) & (y < H_) & (xc >= 0) & (xc < W_);
    int c0 = (step & 3) * 32 + wv * 8;
    const float* pl = xb + ((ptrdiff_t)c0 * HW + y * W_ + xc);
#pragma unroll
    for (int j = 0; j < 8; ++j) { gv[j] = ok ? *pl : 0.f; pl += HW; }
  };

  auto patch_finish = [&](int nb) {
    uint res[4];
#pragma unroll
    for (int j = 0; j < 8; ++j) {
      uint bf = (uint)f2bf(gv[j]);
      if (j & 1) res[j >> 1] |= bf << 16; else res[j >> 1] = bf;
    }
    *(int4*)&s_val[nb][lane][wv * 4] = *(int4*)&res[0];
  };

  auto mfma_step = [&](int step, int cb) {
    bf16x8 af = *(const bf16x8*)(abase + step * 32);
#pragma unroll
    for (int n = 0; n < 4; ++n) {
      bf16x8 bfr = *(const bf16x8*)&s_val[cb][n * 16 + (lane & 15)][(lane >> 4) * 4];
      acc[n] = __builtin_amdgcn_mfma_f32_16x16x32_bf16(af, bfr, acc[n], 0, 0, 0);
    }
  };

  patch_gather(0);
  patch_finish(0);
  __syncthreads();
  for (int it = 0; it < NKS - 1; ++it) {
    patch_gather(it + 1);
    mfma_step(it, it & 1);
    patch_finish((it + 1) & 1);
    __syncthreads();
  }
  mfma_step(NKS - 1, (NKS - 1) & 1);

  int col = lane & 15, rgrp = lane >> 4;
#pragma unroll
  for (int n = 0; n < 4; ++n)
#pragma unroll
    for (int ri = 0; ri < 4; ++ri) {
      int o2 = wv * 16 + rgrp * 4 + ri;
      int g = o2 >> 5, j = o2 & 31;
      if (j < 27) {
        int ch = g * 27 + j;
        om[((size_t)(b * OMCH + ch) * HO + ho) * WO + wo0 + n * 16 + col] =
            acc[n][ri] + b_offset[ch];
      }
    }
}

// ---------------------------------------------------------------------------
// Main kernel: 64 px x 128 Cout, 1152 blocks, K in 9 chunks of 128 r.
// LDS 50.7 KB -> 3 blocks/CU. Val rows padded to 18 uints: b128 reads walk
// all bank groups (conflict-free), writes 2-way (free). Double-buffered,
// ONE barrier per chunk; packed __hfma2 combine; mfma_f32_16x16x32_f16.
// ---------------------------------------------------------------------------
__global__ __launch_bounds__(256, 3) void deform_main_k(
    const __half* __restrict__ xT, const float* __restrict__ om,
    const ushort* __restrict__ WtA, float* __restrict__ out) {
  __shared__ uint  s_addr[18 * 64];               // 4608 B
  __shared__ uint2 s_wq[18 * 64];                 // 9216 B
  __shared__ uint  s_val[2][CSTEP * 64 * VROW];   // 2 x 18432 B

  int bid = blockIdx.x;
  int blk = (bid & 7) * 144 + (bid >> 3);    // bijective, 1152 % 8 == 0
  int wt = blk % 3, bh = blk / 3;
  int ho = bh % HO, b = bh / HO;
  int wo0 = wt * 64;
  int tid = threadIdx.x;
  int lane = tid & 63, wv = tid >> 6;

  // ---- phase 0: canonical in-bounds bilinear coefficients (proven math) ----
  for (int e = tid; e < 18 * 64; e += 256) {
    int px = e & 63, gk = e >> 6;
    int g = gk / 9, k = gk - g * 9;
    int wo = wo0 + px;
    const float* omb = om + (size_t)b * OMCH * HW + (size_t)ho * WO + wo;
    float offy = omb[(size_t)(g * 18 + k * 2 + 0) * HW];
    float offx = omb[(size_t)(g * 18 + k * 2 + 1) * HW];
    float z    = omb[(size_t)(36 + g * 9 + k) * HW];
    float msk  = 2.f / (1.f + __expf(-z));
    float py = (float)(ho - 2 + (k / 3) * 2) + offy;
    float px_ = (float)(wo - 2 + (k % 3) * 2) + offx;
    float y0f = floorf(py), x0f = floorf(px_);
    int   y0 = (int)y0f, x0 = (int)x0f;
    float ty = py - y0f, tx = px_ - x0f;
    float wy0 = (y0 >= 0 && y0 < H_)      ? (1.f - ty) : 0.f;
    float wy1 = (y0 >= -1 && y0 < H_ - 1) ? ty         : 0.f;
    float wx0 = (x0 >= 0 && x0 < W_)      ? (1.f - tx) : 0.f;
    float wx1 = (x0 >= -1 && x0 < W_ - 1) ? tx         : 0.f;
    int yb  = min(max(y0, 0), H_ - 2);
    int xb_ = min(max(x0, 0), W_ - 2);
    float wAy = (y0 == yb      ? wy0 : 0.f) + (y0 + 1 == yb      ? wy1 : 0.f);
    float wBy = (y0 == yb + 1  ? wy0 : 0.f) + (y0 + 1 == yb + 1  ? wy1 : 0.f);
    float wAx = (x0 == xb_     ? wx0 : 0.f) + (x0 + 1 == xb_     ? wx1 : 0.f);
    float wBx = (x0 == xb_ + 1 ? wx0 : 0.f) + (x0 + 1 == xb_ + 1 ? wx1 : 0.f);
    s_addr[e] = (uint)((yb * W_ + xb_) * 128);
    union { __half2 h; uint u; } uA, uB;
    uA.h = __half2{__float2half(wAy * wAx * msk), __float2half(wAy * wBx * msk)};
    uB.h = __half2{__float2half(wBy * wAx * msk), __float2half(wBy * wBx * msk)};
    s_wq[e] = make_uint2(uA.u, uB.u);
  }

  const __half* xTb = xT + (size_t)b * HW * 128;
  int sub = lane >> 3, q = lane & 7;     // px-sub(8), ch-oct(8)
  int col = lane & 15, oct = lane >> 4;  // GEMM lane roles

  f32x4 acc[2][4];
#pragma unroll
  for (int m = 0; m < 2; ++m)
#pragma unroll
    for (int n = 0; n < 4; ++n) acc[m][n] = (f32x4){0.f, 0.f, 0.f, 0.f};

  // per-task state for one chunk (4 tasks, statically indexed)
  uint4 C0[4], C1[4], C2[4], C3[4];
  uint2 WQ[4];
  int   IX[4];

  // issue all 16 gather loads of chunk c (lane covers 8 ch of one px)
  auto issue_chunk = [&](int c) {
#pragma unroll
    for (int t = 0; t < 4; ++t) {
      int idx = wv * 4 + t;              // 0..15
      int gkl = idx >> 3, po = idx & 7;
      int gk = c * 2 + gkl;
      int px = po * 8 + sub;
      int ci = gk * 64 + px;
      uint base = s_addr[ci];
      WQ[t] = s_wq[ci];
      int g = gk >= 9;
      const __half* p = xTb + base + g * 64 + q * 8;
      C0[t] = *(const uint4*)(p);
      C1[t] = *(const uint4*)(p + 128);
      C2[t] = *(const uint4*)(p + W_ * 128);
      C3[t] = *(const uint4*)(p + W_ * 128 + 128);
      int step_local = 2 * gkl + (q >> 2);   // step - 4c
      int row = step_local * 64 + px;
      IX[t] = row * VROW + (q & 3) * 4;
    }
  };

  // packed-f16 bilinear combine + LDS write
  auto finish_chunk = [&](int nb) {
#pragma unroll
    for (int t = 0; t < 4; ++t) {
      union { __half2 h; uint u; } w0, w1;
      w0.u = WQ[t].x; w1.u = WQ[t].y;
      __half2 wAx = __low2half2(w0.h), wAy = __high2half2(w0.h);
      __half2 wBx = __low2half2(w1.h), wBy = __high2half2(w1.h);
      uint res[4];
      const uint* a  = (const uint*)&C0[t];
      const uint* b1 = (const uint*)&C1[t];
      const uint* c2 = (const uint*)&C2[t];
      const uint* d  = (const uint*)&C3[t];
#pragma unroll
      for (int h = 0; h < 4; ++h) {
        union { __half2 h2; uint u; } p0, p1, p2, p3, vv;
        p0.u = a[h]; p1.u = b1[h]; p2.u = c2[h]; p3.u = d[h];
        __half2 v = __hmul2(p0.h2, wAx);
        v = __hfma2(p1.h2, wAy, v);
        v = __hfma2(p2.h2, wBx, v);
        v = __hfma2(p3.h2, wBy, v);
        vv.h2 = v;
        res[h] = vv.u;
      }
      *(uint4*)&s_val[nb][IX[t]] = make_uint4(res[0], res[1], res[2], res[3]);
    }
  };

  // 32 MFMA of chunk c from buffer cb, A coalesced from WtA
  auto mfma_chunk = [&](int c, int cb) {
#pragma unroll
    for (int ls = 0; ls < CSTEP; ++ls) {
      int s = c * CSTEP + ls;
      const ushort* ab = WtA + (size_t)((s * 4 + wv) * 2) * 512 + (oct * 16 + col) * 8;
      f16x8 a0 = *(const f16x8*)(ab);
      f16x8 a1 = *(const f16x8*)(ab + 512);
#pragma unroll
      for (int n = 0; n < 4; ++n) {
        f16x8 bfr = *(const f16x8*)
            &s_val[cb][(ls * 64 + n * 16 + col) * VROW + oct * 4];
        acc[0][n] = __builtin_amdgcn_mfma_f32_16x16x32_f16(a0, bfr, acc[0][n], 0, 0, 0);
        acc[1][n] = __builtin_amdgcn_mfma_f32_16x16x32_f16(a1, bfr, acc[1][n], 0, 0, 0);
      }
    }
  };

  __syncthreads();                  // coeffs ready
  issue_chunk(0);
  finish_chunk(0);
  __syncthreads();                  // buf0 ready

  for (int c = 0; c < NCH; ++c) {
    if (c < NCH - 1) issue_chunk(c + 1);   // loads in flight across MFMA block
    mfma_chunk(c, c & 1);
    if (c < NCH - 1) finish_chunk((c + 1) & 1);
    __syncthreads();
  }

  // ---- epilogue: C/D col=lane&15 (px), row=oct*4+reg (Cout) ----
#pragma unroll
  for (int m = 0; m < 2; ++m)
#pragma unroll
    for (int n = 0; n < 4; ++n)
#pragma unroll
      for (int ri = 0; ri < 4; ++ri) {
        int o = wv * 32 + m * 16 + oct * 4 + ri;
        out[((size_t)(b * COUT + o) * HO + ho) * WO + wo0 + n * 16 + col] = acc[m][n][ri];
      }
}

// ---------------------------------------------------------------------------
extern "C" void kernel_launch(void* const* d_in, const int* in_sizes, int n_in,
                              void* d_out, int out_size, void* d_ws, size_t ws_size,
                              hipStream_t stream) {
  const float* x        = (const float*)d_in[0];
  const float* w_offset = (const float*)d_in[1];
  const float* b_offset = (const float*)d_in[2];
  const float* w_deform = (const float*)d_in[3];
  float* out = (float*)d_out;

  char* ws = (char*)d_ws;
  float*  om  = (float*)ws;                             // 15,925,248 B
  ushort* WtA = (ushort*)(ws + 15925248);               //    294,912 B
  ushort* Awo = (ushort*)(ws + 15925248 + 294912);      //    147,456 B
  __half* xT  = (__half*)(ws + 15925248 + 294912 + 147456);  // 18,874,368 B

  prep_k<<<576, 256, 0, stream>>>(w_deform, w_offset, WtA, Awo);
  xt_k<<<1152, 256, 0, stream>>>(x, xT);
  offset_mfma_k<<<1152, 256, 0, stream>>>(x, Awo, b_offset, om);
  deform_main_k<<<1152, 256, 0, stream>>>(xT, om, WtA, out);
}

// Round 15
// 92.047 us; speedup vs baseline: 3.6875x; 1.2173x over previous
//
#include <hip/hip_runtime.h>
#include <hip/hip_fp16.h>
#include <math.h>

#define BB   4
#define C_   128
#define H_   96
#define W_   192
#define COUT 128
#define DG_  2
#define CG_  64
#define K_   9
#define HO   96
#define WO   192
#define HW   (H_ * W_)       // 18432
#define OMCH 54
#define RDIM (C_ * K_)       // 1152
#define NKS  (RDIM / 32)     // 36 K-steps
#define CSTEP 4              // K-steps per chunk
#define NCH  (NKS / CSTEP)   // 9 chunks
#define VROW 18              // padded uints per val row (bank-walk stride)

typedef __attribute__((ext_vector_type(8))) _Float16 f16x8;
typedef __attribute__((ext_vector_type(4))) float f32x4;

static __device__ __forceinline__ ushort f2bf(float f) {
  union { float f; uint u; } v; v.f = f;
  uint r = v.u + 0x7fff + ((v.u >> 16) & 1);   // RNE
  return (ushort)(r >> 16);
}

// ---------------------------------------------------------------------------
// Prep: WtA  = main-GEMM A, fragment-major f16 (R12-proven layout, M=128);
//       Awo2 = offset-GEMM A, fragment-major f16 (M=64: rows g*32+j, j<27).
// ---------------------------------------------------------------------------
__global__ __launch_bounds__(256) void prep_k(
    const float* __restrict__ wd, const float* __restrict__ wo,
    ushort* __restrict__ WtA, ushort* __restrict__ Awo2) {
  int i = blockIdx.x * 256 + threadIdx.x;
  if (i < 128 * RDIM) {
    int blkA = i >> 9, within = i & 511;
    int oct = within >> 7, colA = (within >> 3) & 15, j = within & 7;
    int m = blkA & 1, wvq = (blkA >> 1) & 3, s = blkA >> 3;
    int o = wvq * 32 + m * 16 + colA;
    int r = s * 32 + oct * 8 + j;
    int g = r / 576, t = r - g * 576;
    int k = t >> 6, cg = t & 63;
    WtA[i] = __half_as_ushort(__float2half(wd[((size_t)o * C_ + g * 64 + cg) * 9 + k]));
  }
  if (i < 64 * RDIM) {
    int blkA = i >> 9, within = i & 511;
    int oct = within >> 7, colA = (within >> 3) & 15, j = within & 7;
    int wv2 = blkA & 3, s = blkA >> 2;
    int o2 = wv2 * 16 + colA;
    int r = s * 32 + oct * 8 + j;
    int g = r / 576, t = r - g * 576;
    int k = t >> 6, cg = t & 63;
    int g2 = o2 >> 5, j2 = o2 & 31;
    float v = ((g2 == g) && (j2 < 27))
                ? wo[(((size_t)(g2 * 27 + j2)) * 64 + cg) * 9 + k] : 0.f;
    Awo2[i] = __half_as_ushort(__float2half(v));
  }
}

// ---------------------------------------------------------------------------
// NCHW -> NHWC fp16 transpose of x (R11-proven).
// ---------------------------------------------------------------------------
__global__ __launch_bounds__(256) void xt_k(
    const float* __restrict__ x, __half* __restrict__ xT) {
  __shared__ float t[128][65];
  int blk = blockIdx.x;
  int b = blk / 288, p0 = (blk % 288) * 64;
  int q = threadIdx.x >> 6, l = threadIdx.x & 63;
  const float* xb = x + (size_t)b * C_ * HW;
#pragma unroll
  for (int it = 0; it < 32; ++it) {
    int c = q * 32 + it;
    t[c][l] = xb[(size_t)c * HW + p0 + l];
  }
  __syncthreads();
  uint* xTb = (uint*)(xT + (size_t)b * HW * 128);
#pragma unroll
  for (int it = 0; it < 16; ++it) {
    int px = q * 16 + it;
    union { __half2 h; uint u; } pk;
    pk.h = __half2{__float2half(t[2 * l][px]), __float2half(t[2 * l + 1][px])};
    xTb[(size_t)(p0 + px) * 64 + l] = pk.u;
  }
}

// ---------------------------------------------------------------------------
// Offset conv, R14-pipeline clone: 64 px x 64 rows (2x27 used), NHWC f16,
// fixed-displacement B loads (1 uint4/task), zero-pad via mask multiply,
// K in 9 chunks, double-buffered VROW-18 LDS, ONE barrier per chunk.
// ---------------------------------------------------------------------------
__global__ __launch_bounds__(256, 4) void offset_nhwc_k(
    const __half* __restrict__ xT, const ushort* __restrict__ Awo2,
    const float* __restrict__ b_offset, float* __restrict__ om) {
  __shared__ uint s_val[2][CSTEP * 64 * VROW];   // 2 x 18432 B

  int bid = blockIdx.x;
  int blk = (bid & 7) * 144 + (bid >> 3);    // bijective, 1152 % 8 == 0
  int wt = blk % 3, bh = blk / 3;
  int ho = bh % HO, b = bh / HO;
  int wo0 = wt * 64;
  int tid = threadIdx.x;
  int lane = tid & 63, wv = tid >> 6;
  int sub = lane >> 3, q = lane & 7;
  int col = lane & 15, oct = lane >> 4;

  const __half* xTb = xT + (size_t)b * HW * 128;

  f32x4 acc[4];
#pragma unroll
  for (int n = 0; n < 4; ++n) acc[n] = (f32x4){0.f, 0.f, 0.f, 0.f};

  uint4 C0[4];
  uint  MK[4];
  int   IX[4];

  auto issue_chunk = [&](int c) {
#pragma unroll
    for (int t = 0; t < 4; ++t) {
      int idx = wv * 4 + t;
      int gkl = idx >> 3, po = idx & 7;
      int gk = c * 2 + gkl;
      int px = po * 8 + sub;
      int g = gk >= 9, k = gk - 9 * g;
      int dy = k / 3, dx = k - dy * 3;
      int y  = ho - 2 + 2 * dy;
      int xc = wo0 + px - 2 + 2 * dx;
      bool ok = (y >= 0) & (y < H_) & (xc >= 0) & (xc < W_);
      int yc  = min(max(y, 0), H_ - 1);
      int xcc = min(max(xc, 0), W_ - 1);
      const __half* p = xTb + (size_t)(yc * W_ + xcc) * 128 + g * 64 + q * 8;
      C0[t] = *(const uint4*)(p);
      MK[t] = ok ? 0x3c003c00u : 0u;     // half2(1,1) or half2(0,0)
      int step_local = 2 * gkl + (q >> 2);
      IX[t] = (step_local * 64 + px) * VROW + (q & 3) * 4;
    }
  };

  auto finish_chunk = [&](int nb) {
#pragma unroll
    for (int t = 0; t < 4; ++t) {
      union { __half2 h2; uint u; } m; m.u = MK[t];
      uint res[4];
      const uint* a = (const uint*)&C0[t];
#pragma unroll
      for (int h = 0; h < 4; ++h) {
        union { __half2 h2; uint u; } p, vv;
        p.u = a[h];
        vv.h2 = __hmul2(p.h2, m.h2);
        res[h] = vv.u;
      }
      *(uint4*)&s_val[nb][IX[t]] = make_uint4(res[0], res[1], res[2], res[3]);
    }
  };

  auto mfma_chunk = [&](int c, int cb) {
#pragma unroll
    for (int ls = 0; ls < CSTEP; ++ls) {
      int s = c * CSTEP + ls;
      const ushort* ab = Awo2 + (size_t)(s * 4 + wv) * 512 + (oct * 16 + col) * 8;
      f16x8 a0 = *(const f16x8*)(ab);
#pragma unroll
      for (int n = 0; n < 4; ++n) {
        f16x8 bfr = *(const f16x8*)
            &s_val[cb][(ls * 64 + n * 16 + col) * VROW + oct * 4];
        acc[n] = __builtin_amdgcn_mfma_f32_16x16x32_f16(a0, bfr, acc[n], 0, 0, 0);
      }
    }
  };

  issue_chunk(0);
  finish_chunk(0);
  __syncthreads();

  for (int c = 0; c < NCH; ++c) {
    if (c < NCH - 1) issue_chunk(c + 1);
    mfma_chunk(c, c & 1);
    if (c < NCH - 1) finish_chunk((c + 1) & 1);
    __syncthreads();
  }

  // epilogue: rows o2 = wv*16 + oct*4 + ri; g=o2>>5, j=o2&31, j<27 real
#pragma unroll
  for (int n = 0; n < 4; ++n)
#pragma unroll
    for (int ri = 0; ri < 4; ++ri) {
      int o2 = wv * 16 + oct * 4 + ri;
      int g = o2 >> 5, j = o2 & 31;
      if (j < 27) {
        int ch = g * 27 + j;
        om[((size_t)(b * OMCH + ch) * HO + ho) * WO + wo0 + n * 16 + col] =
            acc[n][ri] + b_offset[ch];
      }
    }
}

// ---------------------------------------------------------------------------
// Main kernel (R14 exact — proven): 64 px x 128 Cout, 9 chunks, VROW-18 pad,
// packed __hfma2 combine, mfma_f32_16x16x32_f16.
// ---------------------------------------------------------------------------
__global__ __launch_bounds__(256, 3) void deform_main_k(
    const __half* __restrict__ xT, const float* __restrict__ om,
    const ushort* __restrict__ WtA, float* __restrict__ out) {
  __shared__ uint  s_addr[18 * 64];               // 4608 B
  __shared__ uint2 s_wq[18 * 64];                 // 9216 B
  __shared__ uint  s_val[2][CSTEP * 64 * VROW];   // 2 x 18432 B

  int bid = blockIdx.x;
  int blk = (bid & 7) * 144 + (bid >> 3);    // bijective, 1152 % 8 == 0
  int wt = blk % 3, bh = blk / 3;
  int ho = bh % HO, b = bh / HO;
  int wo0 = wt * 64;
  int tid = threadIdx.x;
  int lane = tid & 63, wv = tid >> 6;

  // ---- phase 0: canonical in-bounds bilinear coefficients (proven math) ----
  for (int e = tid; e < 18 * 64; e += 256) {
    int px = e & 63, gk = e >> 6;
    int g = gk / 9, k = gk - g * 9;
    int wo = wo0 + px;
    const float* omb = om + (size_t)b * OMCH * HW + (size_t)ho * WO + wo;
    float offy = omb[(size_t)(g * 18 + k * 2 + 0) * HW];
    float offx = omb[(size_t)(g * 18 + k * 2 + 1) * HW];
    float z    = omb[(size_t)(36 + g * 9 + k) * HW];
    float msk  = 2.f / (1.f + __expf(-z));
    float py = (float)(ho - 2 + (k / 3) * 2) + offy;
    float px_ = (float)(wo - 2 + (k % 3) * 2) + offx;
    float y0f = floorf(py), x0f = floorf(px_);
    int   y0 = (int)y0f, x0 = (int)x0f;
    float ty = py - y0f, tx = px_ - x0f;
    float wy0 = (y0 >= 0 && y0 < H_)      ? (1.f - ty) : 0.f;
    float wy1 = (y0 >= -1 && y0 < H_ - 1) ? ty         : 0.f;
    float wx0 = (x0 >= 0 && x0 < W_)      ? (1.f - tx) : 0.f;
    float wx1 = (x0 >= -1 && x0 < W_ - 1) ? tx         : 0.f;
    int yb  = min(max(y0, 0), H_ - 2);
    int xb_ = min(max(x0, 0), W_ - 2);
    float wAy = (y0 == yb      ? wy0 : 0.f) + (y0 + 1 == yb      ? wy1 : 0.f);
    float wBy = (y0 == yb + 1  ? wy0 : 0.f) + (y0 + 1 == yb + 1  ? wy1 : 0.f);
    float wAx = (x0 == xb_     ? wx0 : 0.f) + (x0 + 1 == xb_     ? wx1 : 0.f);
    float wBx = (x0 == xb_ + 1 ? wx0 : 0.f) + (x0 + 1 == xb_ + 1 ? wx1 : 0.f);
    s_addr[e] = (uint)((yb * W_ + xb_) * 128);
    union { __half2 h; uint u; } uA, uB;
    uA.h = __half2{__float2half(wAy * wAx * msk), __float2half(wAy * wBx * msk)};
    uB.h = __half2{__float2half(wBy * wAx * msk), __float2half(wBy * wBx * msk)};
    s_wq[e] = make_uint2(uA.u, uB.u);
  }

  const __half* xTb = xT + (size_t)b * HW * 128;
  int sub = lane >> 3, q = lane & 7;     // px-sub(8), ch-oct(8)
  int col = lane & 15, oct = lane >> 4;  // GEMM lane roles

  f32x4 acc[2][4];
#pragma unroll
  for (int m = 0; m < 2; ++m)
#pragma unroll
    for (int n = 0; n < 4; ++n) acc[m][n] = (f32x4){0.f, 0.f, 0.f, 0.f};

  uint4 C0[4], C1[4], C2[4], C3[4];
  uint2 WQ[4];
  int   IX[4];

  auto issue_chunk = [&](int c) {
#pragma unroll
    for (int t = 0; t < 4; ++t) {
      int idx = wv * 4 + t;              // 0..15
      int gkl = idx >> 3, po = idx & 7;
      int gk = c * 2 + gkl;
      int px = po * 8 + sub;
      int ci = gk * 64 + px;
      uint base = s_addr[ci];
      WQ[t] = s_wq[ci];
      int g = gk >= 9;
      const __half* p = xTb + base + g * 64 + q * 8;
      C0[t] = *(const uint4*)(p);
      C1[t] = *(const uint4*)(p + 128);
      C2[t] = *(const uint4*)(p + W_ * 128);
      C3[t] = *(const uint4*)(p + W_ * 128 + 128);
      int step_local = 2 * gkl + (q >> 2);
      int row = step_local * 64 + px;
      IX[t] = row * VROW + (q & 3) * 4;
    }
  };

  auto finish_chunk = [&](int nb) {
#pragma unroll
    for (int t = 0; t < 4; ++t) {
      union { __half2 h; uint u; } w0, w1;
      w0.u = WQ[t].x; w1.u = WQ[t].y;
      __half2 wAx = __low2half2(w0.h), wAy = __high2half2(w0.h);
      __half2 wBx = __low2half2(w1.h), wBy = __high2half2(w1.h);
      uint res[4];
      const uint* a  = (const uint*)&C0[t];
      const uint* b1 = (const uint*)&C1[t];
      const uint* c2 = (const uint*)&C2[t];
      const uint* d  = (const uint*)&C3[t];
#pragma unroll
      for (int h = 0; h < 4; ++h) {
        union { __half2 h2; uint u; } p0, p1, p2, p3, vv;
        p0.u = a[h]; p1.u = b1[h]; p2.u = c2[h]; p3.u = d[h];
        __half2 v = __hmul2(p0.h2, wAx);
        v = __hfma2(p1.h2, wAy, v);
        v = __hfma2(p2.h2, wBx, v);
        v = __hfma2(p3.h2, wBy, v);
        vv.h2 = v;
        res[h] = vv.u;
      }
      *(uint4*)&s_val[nb][IX[t]] = make_uint4(res[0], res[1], res[2], res[3]);
    }
  };

  auto mfma_chunk = [&](int c, int cb) {
#pragma unroll
    for (int ls = 0; ls < CSTEP; ++ls) {
      int s = c * CSTEP + ls;
      const ushort* ab = WtA + (size_t)((s * 4 + wv) * 2) * 512 + (oct * 16 + col) * 8;
      f16x8 a0 = *(const f16x8*)(ab);
      f16x8 a1 = *(const f16x8*)(ab + 512);
#pragma unroll
      for (int n = 0; n < 4; ++n) {
        f16x8 bfr = *(const f16x8*)
            &s_val[cb][(ls * 64 + n * 16 + col) * VROW + oct * 4];
        acc[0][n] = __builtin_amdgcn_mfma_f32_16x16x32_f16(a0, bfr, acc[0][n], 0, 0, 0);
        acc[1][n] = __builtin_amdgcn_mfma_f32_16x16x32_f16(a1, bfr, acc[1][n], 0, 0, 0);
      }
    }
  };

  __syncthreads();                  // coeffs ready
  issue_chunk(0);
  finish_chunk(0);
  __syncthreads();                  // buf0 ready

  for (int c = 0; c < NCH; ++c) {
    if (c < NCH - 1) issue_chunk(c + 1);
    mfma_chunk(c, c & 1);
    if (c < NCH - 1) finish_chunk((c + 1) & 1);
    __syncthreads();
  }

  // ---- epilogue ----
#pragma unroll
  for (int m = 0; m < 2; ++m)
#pragma unroll
    for (int n = 0; n < 4; ++n)
#pragma unroll
      for (int ri = 0; ri < 4; ++ri) {
        int o = wv * 32 + m * 16 + oct * 4 + ri;
        out[((size_t)(b * COUT + o) * HO + ho) * WO + wo0 + n * 16 + col] = acc[m][n][ri];
      }
}

// ---------------------------------------------------------------------------
extern "C" void kernel_launch(void* const* d_in, const int* in_sizes, int n_in,
                              void* d_out, int out_size, void* d_ws, size_t ws_size,
                              hipStream_t stream) {
  const float* x        = (const float*)d_in[0];
  const float* w_offset = (const float*)d_in[1];
  const float* b_offset = (const float*)d_in[2];
  const float* w_deform = (const float*)d_in[3];
  float* out = (float*)d_out;

  char* ws = (char*)d_ws;
  float*  om   = (float*)ws;                             // 15,925,248 B
  ushort* WtA  = (ushort*)(ws + 15925248);               //    294,912 B
  ushort* Awo2 = (ushort*)(ws + 15925248 + 294912);      //    147,456 B
  __half* xT   = (__half*)(ws + 15925248 + 294912 + 147456);  // 18,874,368 B

  prep_k<<<576, 256, 0, stream>>>(w_deform, w_offset, WtA, Awo2);
  xt_k<<<1152, 256, 0, stream>>>(x, xT);
  offset_nhwc_k<<<1152, 256, 0, stream>>>(xT, Awo2, b_offset, om);
  deform_main_k<<<1152, 256, 0, stream>>>(xT, om, WtA, out);
}